// Round 3
// baseline (1638.129 us; speedup 1.0000x reference)
//
#include <hip/hip_runtime.h>

#define NDIM 14
#define HDIM 64

static __device__ __forceinline__ float sigmoidf_(float x) { return 1.f / (1.f + __expf(-x)); }

// ======================= CSR build (counting sort by dst) =======================
__global__ void k_zero(int* __restrict__ deg, int* __restrict__ cursor, int N) {
  int i = blockIdx.x * blockDim.x + threadIdx.x;
  if (i < N) deg[i] = 0;
  if (i == 0) *cursor = 0;
}

__global__ void k_count(const int* __restrict__ ei, int* __restrict__ deg, int E) {
  int e = blockIdx.x * blockDim.x + threadIdx.x;
  if (e < E) atomicAdd(&deg[ei[E + e]], 1);
}

// segment allocation: wave-level inclusive scan of degrees, one global atomic per wave
__global__ void k_alloc(const int* __restrict__ deg, int* __restrict__ row_off,
                        int* __restrict__ cur, int* __restrict__ cursor, int N) {
  int n = blockIdx.x * blockDim.x + threadIdx.x;
  int lane = threadIdx.x & 63;
  int d = (n < N) ? deg[n] : 0;
  int x = d;
#pragma unroll
  for (int m = 1; m <= 32; m <<= 1) {
    int t = __shfl_up(x, m, 64);
    if (lane >= m) x += t;
  }
  int wave_total = __shfl(x, 63, 64);
  int base = 0;
  if (lane == 63) base = atomicAdd(cursor, wave_total);
  base = __shfl(base, 63, 64);
  if (n < N) {
    int start = base + x - d;   // exclusive scan
    row_off[n] = start;
    cur[n] = start;
  }
}

__global__ void k_scatter(const int* __restrict__ ei, int* __restrict__ cur,
                          int* __restrict__ csr_src, int E) {
  int e = blockIdx.x * blockDim.x + threadIdx.x;
  if (e < E) {
    int d = ei[E + e];
    int p = atomicAdd(&cur[d], 1);
    csr_src[p] = ei[e];
  }
}

// ======================= k0: fold proj into layer-1 weights =======================
// Wfl = projW @ Wl  (14x64), bfl = projB @ Wl (64); likewise r.
__global__ void k0_fuse(const float* __restrict__ projW, const float* __restrict__ projB,
                        const float* __restrict__ Wl, const float* __restrict__ Wr,
                        float* __restrict__ Wfl, float* __restrict__ Wfr,
                        float* __restrict__ bfl, float* __restrict__ bfr) {
  int t = blockIdx.x * blockDim.x + threadIdx.x;
  int total = (NDIM + 1) * HDIM;      // rows 0..13 = weights, row 14 = bias
  if (t >= total) return;
  int r = t / HDIM, c = t % HDIM;
  float al = 0.f, ar = 0.f;
  if (r < NDIM) {
    for (int k = 0; k < HDIM; ++k) {
      float w = projW[r * HDIM + k];
      al += w * Wl[k * HDIM + c];
      ar += w * Wr[k * HDIM + c];
    }
    Wfl[r * HDIM + c] = al;
    Wfr[r * HDIM + c] = ar;
  } else {
    for (int k = 0; k < HDIM; ++k) {
      float w = projB[k];
      al += w * Wl[k * HDIM + c];
      ar += w * Wr[k * HDIM + c];
    }
    bfl[c] = al;
    bfr[c] = ar;
  }
}

// ======================= k1: XL1/XR1 directly from node features =======================
__global__ void k1_xlxr(const float* __restrict__ nf, const float* __restrict__ Wfl,
                        const float* __restrict__ Wfr, const float* __restrict__ bfl,
                        const float* __restrict__ bfr, float* __restrict__ XL,
                        float* __restrict__ XR, int N) {
  int n = blockIdx.x * (blockDim.x >> 6) + (threadIdx.x >> 6);
  int j = threadIdx.x & 63;
  if (n >= N) return;
  float nfv = (j < NDIM) ? nf[n * NDIM + j] : 0.f;
  float al = bfl[j], ar = bfr[j];
#pragma unroll
  for (int k = 0; k < NDIM; ++k) {
    float xk = __shfl(nfv, k, 64);
    al += xk * Wfl[k * HDIM + j];
    ar += xk * Wfr[k * HDIM + j];
  }
  XL[n * HDIM + j] = al;
  XR[n * HDIM + j] = ar;
}

// ======================= k_agg: pull-aggregate + softmax + ELU + LN =======================
// wave per node; lane j = h*32+c. Zero atomics.
__global__ void k_agg(const int* __restrict__ csr_src, const int* __restrict__ row_off,
                      const int* __restrict__ deg, const float* __restrict__ XL,
                      const float* __restrict__ XR, const float* __restrict__ att,
                      const float* __restrict__ gb, const float* __restrict__ lng,
                      const float* __restrict__ lnb, float* __restrict__ Y, int N) {
  int n = blockIdx.x * (blockDim.x >> 6) + (threadIdx.x >> 6);
  int j = threadIdx.x & 63;
  if (n >= N) return;
  float xr = XR[n * HDIM + j];
  float attv = att[j];

  // self-loop (reference appends it explicitly)
  float xl = XL[n * HDIM + j];
  float v = xl + xr;
  v = v > 0.f ? v : 0.2f * v;
  float p = v * attv;
#pragma unroll
  for (int m = 16; m >= 1; m >>= 1) p += __shfl_xor(p, m, 64);
  float ex = __expf(p);
  float acc = ex * xl;
  float den = ex;

  int base = row_off[n], cnt = deg[n];
  for (int c0 = 0; c0 < cnt; c0 += 64) {
    int m_ = cnt - c0; if (m_ > 64) m_ = 64;
    int sidx = (j < m_) ? csr_src[base + c0 + j] : 0;   // coalesced index read
    for (int t = 0; t < m_; ++t) {
      int s = __shfl(sidx, t, 64);
      float xls = XL[s * HDIM + j];
      float vv = xls + xr;
      vv = vv > 0.f ? vv : 0.2f * vv;
      float pp = vv * attv;
#pragma unroll
      for (int m = 16; m >= 1; m >>= 1) pp += __shfl_xor(pp, m, 64);
      float ee = __expf(pp);
      acc += ee * xls;
      den += ee;
    }
  }

  // epilogue: divide, +bias, ELU, LayerNorm
  float y = acc / (den + 1e-16f) + gb[j];
  y = y > 0.f ? y : __expf(y) - 1.f;
  float s_ = y;
#pragma unroll
  for (int m = 32; m >= 1; m >>= 1) s_ += __shfl_xor(s_, m, 64);
  float mu = s_ * (1.f / 64.f);
  float d = y - mu;
  float sq = d * d;
#pragma unroll
  for (int m = 32; m >= 1; m >>= 1) sq += __shfl_xor(sq, m, 64);
  Y[n * HDIM + j] = d * rsqrtf(sq * (1.f / 64.f) + 1e-5f) * lng[j] + lnb[j];
}

// ======================= k3: Y -> XL2/XR2 (LDS-staged weights) =======================
__global__ void k3_lr(const float* __restrict__ Y, const float* __restrict__ Wl,
                      const float* __restrict__ Wr, float* __restrict__ XL,
                      float* __restrict__ XR, int N) {
  __shared__ float Wls[HDIM * HDIM];
  __shared__ float Wrs[HDIM * HDIM];
  for (int i = threadIdx.x; i < HDIM * HDIM; i += blockDim.x) {
    Wls[i] = Wl[i];
    Wrs[i] = Wr[i];
  }
  __syncthreads();
  int n = blockIdx.x * (blockDim.x >> 6) + (threadIdx.x >> 6);
  int j = threadIdx.x & 63;
  if (n >= N) return;
  float y = Y[n * HDIM + j];
  float al = 0.f, ar = 0.f;
#pragma unroll
  for (int k = 0; k < HDIM; ++k) {
    float xk = __shfl(y, k, 64);
    al += xk * Wls[k * HDIM + j];
    ar += xk * Wrs[k * HDIM + j];
  }
  XL[n * HDIM + j] = al;
  XR[n * HDIM + j] = ar;
}

// ======================= k5: GRU (h0=0) + 4 heads =======================
__global__ void k5_gru(const float* __restrict__ Y, const float* __restrict__ Wi,
                       const float* __restrict__ bi, const float* __restrict__ bh,
                       const float* __restrict__ huW, const float* __restrict__ hub,
                       const float* __restrict__ hfW, const float* __restrict__ hfb,
                       const float* __restrict__ hoW, const float* __restrict__ hob,
                       const float* __restrict__ hcW, const float* __restrict__ hcb,
                       float* __restrict__ out, int N) {
  __shared__ float Wis[HDIM * 192];
  for (int i = threadIdx.x; i < HDIM * 192; i += blockDim.x) Wis[i] = Wi[i];
  __syncthreads();
  int n = blockIdx.x * (blockDim.x >> 6) + (threadIdx.x >> 6);
  int j = threadIdx.x & 63;
  if (n >= N) return;
  float y = Y[n * HDIM + j];
  float ar = 0.f, az = 0.f, an = 0.f;
#pragma unroll
  for (int k = 0; k < HDIM; ++k) {
    float xk = __shfl(y, k, 64);
    ar += xk * Wis[k * 192 + j];
    az += xk * Wis[k * 192 + 64 + j];
    an += xk * Wis[k * 192 + 128 + j];
  }
  float r = sigmoidf_(ar + bi[j] + bh[j]);
  float z = sigmoidf_(az + bi[64 + j] + bh[64 + j]);
  float nn = tanhf(an + bi[128 + j] + r * bh[128 + j]);
  float hv = (1.f - z) * nn;
  float pu = hv * huW[j], pf = hv * hfW[j], po = hv * hoW[j], pc = hv * hcW[j];
#pragma unroll
  for (int m = 32; m >= 1; m >>= 1) {
    pu += __shfl_xor(pu, m, 64);
    pf += __shfl_xor(pf, m, 64);
    po += __shfl_xor(po, m, 64);
    pc += __shfl_xor(pc, m, 64);
  }
  if (j == 0) {
    out[n]         = sigmoidf_(pu + hub[0]);
    out[N + n]     = sigmoidf_(pf + hfb[0]);
    out[2 * N + n] = fmaxf(po + hob[0], 0.f);
    out[3 * N + n] = sigmoidf_(pc + hcb[0]);
  }
}

// ======================= launch =======================
extern "C" void kernel_launch(void* const* d_in, const int* in_sizes, int n_in,
                              void* d_out, int out_size, void* d_ws, size_t ws_size,
                              hipStream_t stream) {
  const float* nf    = (const float*)d_in[0];
  const int*   ei    = (const int*)d_in[1];
  const float* projW = (const float*)d_in[2];
  const float* projB = (const float*)d_in[3];
  const float* g1Wl  = (const float*)d_in[4];
  const float* g1Wr  = (const float*)d_in[5];
  const float* g1att = (const float*)d_in[6];
  const float* g1b   = (const float*)d_in[7];
  const float* g2Wl  = (const float*)d_in[8];
  const float* g2Wr  = (const float*)d_in[9];
  const float* g2att = (const float*)d_in[10];
  const float* g2b   = (const float*)d_in[11];
  const float* ln1g  = (const float*)d_in[12];
  const float* ln1b  = (const float*)d_in[13];
  const float* ln2g  = (const float*)d_in[14];
  const float* ln2b  = (const float*)d_in[15];
  const float* gruWi = (const float*)d_in[16];
  // d_in[17] = gru_Wh, unused (h0 = 0)
  const float* gruBi = (const float*)d_in[18];
  const float* gruBh = (const float*)d_in[19];
  const float* huW = (const float*)d_in[20];
  const float* hub = (const float*)d_in[21];
  const float* hfW = (const float*)d_in[22];
  const float* hfb = (const float*)d_in[23];
  const float* hoW = (const float*)d_in[24];
  const float* hob = (const float*)d_in[25];
  const float* hcW = (const float*)d_in[26];
  const float* hcb = (const float*)d_in[27];
  float* out = (float*)d_out;

  const int N = in_sizes[0] / NDIM;
  const int E = in_sizes[1] / 2;

  // workspace carve-up
  char* ws = (char*)d_ws;
  size_t off = 0;
  auto carve = [&](size_t bytes) { void* p = ws + off; off += (bytes + 255) & ~size_t(255); return p; };
  float* XL      = (float*)carve(sizeof(float) * N * HDIM);
  float* XR      = (float*)carve(sizeof(float) * N * HDIM);
  float* Y       = (float*)carve(sizeof(float) * N * HDIM);
  int*   csr_src = (int*)carve(sizeof(int) * E);
  int*   deg     = (int*)carve(sizeof(int) * N);
  int*   row_off = (int*)carve(sizeof(int) * N);
  int*   cur     = (int*)carve(sizeof(int) * N);
  int*   cursor  = (int*)carve(sizeof(int) * 64);
  float* Wfl     = (float*)carve(sizeof(float) * NDIM * HDIM);
  float* Wfr     = (float*)carve(sizeof(float) * NDIM * HDIM);
  float* bfl     = (float*)carve(sizeof(float) * HDIM);
  float* bfr     = (float*)carve(sizeof(float) * HDIM);

  const int BLK = 256;
  dim3 b(BLK);
  dim3 gridN((N + BLK - 1) / BLK);
  dim3 gridE((E + BLK - 1) / BLK);
  dim3 gridWaveN((N + 3) / 4);   // 4 waves/block, wave per node

  // ---- CSR build ----
  k_zero<<<gridN, b, 0, stream>>>(deg, cursor, N);
  k_count<<<gridE, b, 0, stream>>>(ei, deg, E);
  k_alloc<<<gridN, b, 0, stream>>>(deg, row_off, cur, cursor, N);
  k_scatter<<<gridE, b, 0, stream>>>(ei, cur, csr_src, E);

  // ---- fold proj into layer-1 weights, then XL1/XR1 ----
  k0_fuse<<<dim3(4), b, 0, stream>>>(projW, projB, g1Wl, g1Wr, Wfl, Wfr, bfl, bfr);
  k1_xlxr<<<gridWaveN, b, 0, stream>>>(nf, Wfl, Wfr, bfl, bfr, XL, XR, N);

  // ---- GAT layer 1 (pull) ----
  k_agg<<<gridWaveN, b, 0, stream>>>(csr_src, row_off, deg, XL, XR, g1att, g1b, ln1g, ln1b, Y, N);
  // ---- layer 2 linear ----
  k3_lr<<<gridWaveN, b, 0, stream>>>(Y, g2Wl, g2Wr, XL, XR, N);
  // ---- GAT layer 2 (pull) ----
  k_agg<<<gridWaveN, b, 0, stream>>>(csr_src, row_off, deg, XL, XR, g2att, g2b, ln2g, ln2b, Y, N);
  // ---- GRU + heads ----
  k5_gru<<<gridWaveN, b, 0, stream>>>(Y, gruWi, gruBi, gruBh,
                                      huW, hub, hfW, hfb, hoW, hob, hcW, hcb, out, N);
}

// Round 4
// 888.072 us; speedup vs baseline: 1.8446x; 1.8446x over previous
//
#include <hip/hip_runtime.h>

#define NDIM 14
#define HDIM 64

static __device__ __forceinline__ float sigmoidf_(float x) { return 1.f / (1.f + __expf(-x)); }
static __device__ __forceinline__ float lrelu_(float x) { return x > 0.f ? x : 0.2f * x; }

// ======================= CSR build (counting sort by dst) =======================
__global__ void k_zero(int* __restrict__ deg, int* __restrict__ cursor, int N) {
  int i = blockIdx.x * blockDim.x + threadIdx.x;
  if (i < N) deg[i] = 0;
  if (i == 0) *cursor = 0;
}

__global__ void k_count(const int* __restrict__ ei, int* __restrict__ deg, int E) {
  int e = blockIdx.x * blockDim.x + threadIdx.x;
  if (e < E) atomicAdd(&deg[ei[E + e]], 1);
}

__global__ void k_alloc(const int* __restrict__ deg, int* __restrict__ row_off,
                        int* __restrict__ cur, int* __restrict__ cursor, int N) {
  int n = blockIdx.x * blockDim.x + threadIdx.x;
  int lane = threadIdx.x & 63;
  int d = (n < N) ? deg[n] : 0;
  int x = d;
#pragma unroll
  for (int m = 1; m <= 32; m <<= 1) {
    int t = __shfl_up(x, m, 64);
    if (lane >= m) x += t;
  }
  int wave_total = __shfl(x, 63, 64);
  int base = 0;
  if (lane == 63) base = atomicAdd(cursor, wave_total);
  base = __shfl(base, 63, 64);
  if (n < N) {
    int start = base + x - d;   // exclusive scan
    row_off[n] = start;
    cur[n] = start;
  }
}

__global__ void k_scatter(const int* __restrict__ ei, int* __restrict__ cur,
                          int* __restrict__ csr_src, int E) {
  int e = blockIdx.x * blockDim.x + threadIdx.x;
  if (e < E) {
    int d = ei[E + e];
    int p = atomicAdd(&cur[d], 1);
    csr_src[p] = ei[e];
  }
}

// ======================= k0: fold proj into layer-1 weights =======================
__global__ void k0_fuse(const float* __restrict__ projW, const float* __restrict__ projB,
                        const float* __restrict__ Wl, const float* __restrict__ Wr,
                        float* __restrict__ Wfl, float* __restrict__ Wfr,
                        float* __restrict__ bfl, float* __restrict__ bfr) {
  int t = blockIdx.x * blockDim.x + threadIdx.x;
  int total = (NDIM + 1) * HDIM;
  if (t >= total) return;
  int r = t / HDIM, c = t % HDIM;
  float al = 0.f, ar = 0.f;
  if (r < NDIM) {
    for (int k = 0; k < HDIM; ++k) {
      float w = projW[r * HDIM + k];
      al += w * Wl[k * HDIM + c];
      ar += w * Wr[k * HDIM + c];
    }
    Wfl[r * HDIM + c] = al;
    Wfr[r * HDIM + c] = ar;
  } else {
    for (int k = 0; k < HDIM; ++k) {
      float w = projB[k];
      al += w * Wl[k * HDIM + c];
      ar += w * Wr[k * HDIM + c];
    }
    bfl[c] = al;
    bfr[c] = ar;
  }
}

// ======================= k1: XL1/XR1 directly from node features =======================
__global__ void k1_xlxr(const float* __restrict__ nf, const float* __restrict__ Wfl,
                        const float* __restrict__ Wfr, const float* __restrict__ bfl,
                        const float* __restrict__ bfr, float* __restrict__ XL,
                        float* __restrict__ XR, int N) {
  int n = blockIdx.x * (blockDim.x >> 6) + (threadIdx.x >> 6);
  int j = threadIdx.x & 63;
  if (n >= N) return;
  float nfv = (j < NDIM) ? nf[n * NDIM + j] : 0.f;
  float al = bfl[j], ar = bfr[j];
#pragma unroll
  for (int k = 0; k < NDIM; ++k) {
    float xk = __shfl(nfv, k, 64);
    al += xk * Wfl[k * HDIM + j];
    ar += xk * Wfr[k * HDIM + j];
  }
  XL[n * HDIM + j] = al;
  XR[n * HDIM + j] = ar;
}

// ======================= k_agg: pull-aggregate + softmax + ELU + LN =======================
// wave per node; lane j = h*32+c. Zero atomics. 4-way edge ILP.
__global__ void k_agg(const int* __restrict__ csr_src, const int* __restrict__ row_off,
                      const int* __restrict__ deg, const float* __restrict__ XL,
                      const float* __restrict__ XR, const float* __restrict__ att,
                      const float* __restrict__ gb, const float* __restrict__ lng,
                      const float* __restrict__ lnb, float* __restrict__ Y, int N) {
  int n = blockIdx.x * (blockDim.x >> 6) + (threadIdx.x >> 6);
  int j = threadIdx.x & 63;
  if (n >= N) return;
  float xr = XR[n * HDIM + j];
  float attv = att[j];

  // self-loop
  float xl = XL[n * HDIM + j];
  float p = lrelu_(xl + xr) * attv;
#pragma unroll
  for (int m = 16; m >= 1; m >>= 1) p += __shfl_xor(p, m, 64);
  float ex = __expf(p);
  float acc = ex * xl;
  float den = ex;

  int base = row_off[n], cnt = deg[n];
  for (int c0 = 0; c0 < cnt; c0 += 64) {
    int m_ = cnt - c0; if (m_ > 64) m_ = 64;
    int sidx = (j < m_) ? csr_src[base + c0 + j] : 0;
    int t = 0;
    for (; t + 4 <= m_; t += 4) {
      int s0 = __shfl(sidx, t, 64), s1 = __shfl(sidx, t + 1, 64);
      int s2 = __shfl(sidx, t + 2, 64), s3 = __shfl(sidx, t + 3, 64);
      float x0 = XL[s0 * HDIM + j], x1 = XL[s1 * HDIM + j];
      float x2 = XL[s2 * HDIM + j], x3 = XL[s3 * HDIM + j];
      float p0 = lrelu_(x0 + xr) * attv, p1 = lrelu_(x1 + xr) * attv;
      float p2 = lrelu_(x2 + xr) * attv, p3 = lrelu_(x3 + xr) * attv;
#pragma unroll
      for (int m = 16; m >= 1; m >>= 1) {
        p0 += __shfl_xor(p0, m, 64);
        p1 += __shfl_xor(p1, m, 64);
        p2 += __shfl_xor(p2, m, 64);
        p3 += __shfl_xor(p3, m, 64);
      }
      float e0 = __expf(p0), e1 = __expf(p1), e2 = __expf(p2), e3 = __expf(p3);
      acc += e0 * x0 + e1 * x1 + e2 * x2 + e3 * x3;
      den += e0 + e1 + e2 + e3;
    }
    for (; t < m_; ++t) {
      int s = __shfl(sidx, t, 64);
      float xls = XL[s * HDIM + j];
      float pp = lrelu_(xls + xr) * attv;
#pragma unroll
      for (int m = 16; m >= 1; m >>= 1) pp += __shfl_xor(pp, m, 64);
      float ee = __expf(pp);
      acc += ee * xls;
      den += ee;
    }
  }

  float y = acc / (den + 1e-16f) + gb[j];
  y = y > 0.f ? y : __expf(y) - 1.f;
  float s_ = y;
#pragma unroll
  for (int m = 32; m >= 1; m >>= 1) s_ += __shfl_xor(s_, m, 64);
  float mu = s_ * (1.f / 64.f);
  float d = y - mu;
  float sq = d * d;
#pragma unroll
  for (int m = 32; m >= 1; m >>= 1) sq += __shfl_xor(sq, m, 64);
  Y[n * HDIM + j] = d * rsqrtf(sq * (1.f / 64.f) + 1e-5f) * lng[j] + lnb[j];
}

// ======================= k3: Y -> XL2/XR2 (persistent, LDS-staged once) =======================
__global__ void __launch_bounds__(256) k3_lr(const float* __restrict__ Y,
                      const float* __restrict__ Wl, const float* __restrict__ Wr,
                      float* __restrict__ XL, float* __restrict__ XR, int N) {
  __shared__ float Wls[HDIM * HDIM];
  __shared__ float Wrs[HDIM * HDIM];
  for (int i = threadIdx.x; i < HDIM * HDIM / 4; i += blockDim.x) {
    ((float4*)Wls)[i] = ((const float4*)Wl)[i];
    ((float4*)Wrs)[i] = ((const float4*)Wr)[i];
  }
  __syncthreads();
  int wave = blockIdx.x * (blockDim.x >> 6) + (threadIdx.x >> 6);
  int nwaves = gridDim.x * (blockDim.x >> 6);
  int j = threadIdx.x & 63;
  for (int n = wave; n < N; n += nwaves) {
    float y = Y[n * HDIM + j];
    float al = 0.f, ar = 0.f;
#pragma unroll
    for (int k = 0; k < HDIM; ++k) {
      float xk = __shfl(y, k, 64);
      al += xk * Wls[k * HDIM + j];
      ar += xk * Wrs[k * HDIM + j];
    }
    XL[n * HDIM + j] = al;
    XR[n * HDIM + j] = ar;
  }
}

// ======================= k5: GRU (h0=0) + 4 heads (persistent, LDS-staged once) =======================
__global__ void __launch_bounds__(256) k5_gru(const float* __restrict__ Y,
                       const float* __restrict__ Wi,
                       const float* __restrict__ bi, const float* __restrict__ bh,
                       const float* __restrict__ huW, const float* __restrict__ hub,
                       const float* __restrict__ hfW, const float* __restrict__ hfb,
                       const float* __restrict__ hoW, const float* __restrict__ hob,
                       const float* __restrict__ hcW, const float* __restrict__ hcb,
                       float* __restrict__ out, int N) {
  __shared__ float Wis[HDIM * 192];
  for (int i = threadIdx.x; i < HDIM * 192 / 4; i += blockDim.x)
    ((float4*)Wis)[i] = ((const float4*)Wi)[i];
  __syncthreads();
  int wave = blockIdx.x * (blockDim.x >> 6) + (threadIdx.x >> 6);
  int nwaves = gridDim.x * (blockDim.x >> 6);
  int j = threadIdx.x & 63;
  float biR = bi[j] + bh[j], biZ = bi[64 + j] + bh[64 + j];
  float biN = bi[128 + j], bhN = bh[128 + j];
  float wu = huW[j], wf = hfW[j], wo = hoW[j], wc = hcW[j];
  for (int n = wave; n < N; n += nwaves) {
    float y = Y[n * HDIM + j];
    float ar = 0.f, az = 0.f, an = 0.f;
#pragma unroll
    for (int k = 0; k < HDIM; ++k) {
      float xk = __shfl(y, k, 64);
      ar += xk * Wis[k * 192 + j];
      az += xk * Wis[k * 192 + 64 + j];
      an += xk * Wis[k * 192 + 128 + j];
    }
    float r = sigmoidf_(ar + biR);
    float z = sigmoidf_(az + biZ);
    float nn = tanhf(an + biN + r * bhN);
    float hv = (1.f - z) * nn;
    float pu = hv * wu, pf = hv * wf, po = hv * wo, pc = hv * wc;
#pragma unroll
    for (int m = 32; m >= 1; m >>= 1) {
      pu += __shfl_xor(pu, m, 64);
      pf += __shfl_xor(pf, m, 64);
      po += __shfl_xor(po, m, 64);
      pc += __shfl_xor(pc, m, 64);
    }
    if (j == 0) {
      out[n]         = sigmoidf_(pu + hub[0]);
      out[N + n]     = sigmoidf_(pf + hfb[0]);
      out[2 * N + n] = fmaxf(po + hob[0], 0.f);
      out[3 * N + n] = sigmoidf_(pc + hcb[0]);
    }
  }
}

// ======================= launch =======================
extern "C" void kernel_launch(void* const* d_in, const int* in_sizes, int n_in,
                              void* d_out, int out_size, void* d_ws, size_t ws_size,
                              hipStream_t stream) {
  const float* nf    = (const float*)d_in[0];
  const int*   ei    = (const int*)d_in[1];
  const float* projW = (const float*)d_in[2];
  const float* projB = (const float*)d_in[3];
  const float* g1Wl  = (const float*)d_in[4];
  const float* g1Wr  = (const float*)d_in[5];
  const float* g1att = (const float*)d_in[6];
  const float* g1b   = (const float*)d_in[7];
  const float* g2Wl  = (const float*)d_in[8];
  const float* g2Wr  = (const float*)d_in[9];
  const float* g2att = (const float*)d_in[10];
  const float* g2b   = (const float*)d_in[11];
  const float* ln1g  = (const float*)d_in[12];
  const float* ln1b  = (const float*)d_in[13];
  const float* ln2g  = (const float*)d_in[14];
  const float* ln2b  = (const float*)d_in[15];
  const float* gruWi = (const float*)d_in[16];
  // d_in[17] = gru_Wh, unused (h0 = 0)
  const float* gruBi = (const float*)d_in[18];
  const float* gruBh = (const float*)d_in[19];
  const float* huW = (const float*)d_in[20];
  const float* hub = (const float*)d_in[21];
  const float* hfW = (const float*)d_in[22];
  const float* hfb = (const float*)d_in[23];
  const float* hoW = (const float*)d_in[24];
  const float* hob = (const float*)d_in[25];
  const float* hcW = (const float*)d_in[26];
  const float* hcb = (const float*)d_in[27];
  float* out = (float*)d_out;

  const int N = in_sizes[0] / NDIM;
  const int E = in_sizes[1] / 2;

  char* ws = (char*)d_ws;
  size_t off = 0;
  auto carve = [&](size_t bytes) { void* p = ws + off; off += (bytes + 255) & ~size_t(255); return p; };
  float* XL      = (float*)carve(sizeof(float) * N * HDIM);
  float* XR      = (float*)carve(sizeof(float) * N * HDIM);
  float* Y       = (float*)carve(sizeof(float) * N * HDIM);
  int*   csr_src = (int*)carve(sizeof(int) * E);
  int*   deg     = (int*)carve(sizeof(int) * N);
  int*   row_off = (int*)carve(sizeof(int) * N);
  int*   cur     = (int*)carve(sizeof(int) * N);
  int*   cursor  = (int*)carve(sizeof(int) * 64);
  float* Wfl     = (float*)carve(sizeof(float) * NDIM * HDIM);
  float* Wfr     = (float*)carve(sizeof(float) * NDIM * HDIM);
  float* bfl     = (float*)carve(sizeof(float) * HDIM);
  float* bfr     = (float*)carve(sizeof(float) * HDIM);

  const int BLK = 256;
  dim3 b(BLK);
  dim3 gridN((N + BLK - 1) / BLK);
  dim3 gridE((E + BLK - 1) / BLK);
  dim3 gridWaveN((N + 3) / 4);   // 4 waves/block, wave per node

  // ---- CSR build ----
  k_zero<<<gridN, b, 0, stream>>>(deg, cursor, N);
  k_count<<<gridE, b, 0, stream>>>(ei, deg, E);
  k_alloc<<<gridN, b, 0, stream>>>(deg, row_off, cur, cursor, N);
  k_scatter<<<gridE, b, 0, stream>>>(ei, cur, csr_src, E);

  // ---- fold proj into layer-1 weights, then XL1/XR1 ----
  k0_fuse<<<dim3(4), b, 0, stream>>>(projW, projB, g1Wl, g1Wr, Wfl, Wfr, bfl, bfr);
  k1_xlxr<<<gridWaveN, b, 0, stream>>>(nf, Wfl, Wfr, bfl, bfr, XL, XR, N);

  // ---- GAT layer 1 (pull) ----
  k_agg<<<gridWaveN, b, 0, stream>>>(csr_src, row_off, deg, XL, XR, g1att, g1b, ln1g, ln1b, Y, N);
  // ---- layer 2 linear: persistent blocks, 5/CU residency at 32KB LDS ----
  k3_lr<<<dim3(1280), b, 0, stream>>>(Y, g2Wl, g2Wr, XL, XR, N);
  // ---- GAT layer 2 (pull) ----
  k_agg<<<gridWaveN, b, 0, stream>>>(csr_src, row_off, deg, XL, XR, g2att, g2b, ln2g, ln2b, Y, N);
  // ---- GRU + heads: persistent blocks, 3/CU residency at 48KB LDS ----
  k5_gru<<<dim3(768), b, 0, stream>>>(Y, gruWi, gruBi, gruBh,
                                      huW, hub, hfW, hfb, hoW, hob, hcW, hcb, out, N);
}

// Round 5
// 711.399 us; speedup vs baseline: 2.3027x; 1.2483x over previous
//
#include <hip/hip_runtime.h>

#define NDIM 14
#define HDIM 64

static __device__ __forceinline__ float sigmoidf_(float x) { return 1.f / (1.f + __expf(-x)); }
static __device__ __forceinline__ float lrelu_(float x) { return x > 0.f ? x : 0.2f * x; }

// readlane broadcast (VALU, no DS pipe). lane must be wave-uniform.
static __device__ __forceinline__ float readlane_f(float x, int lane) {
  return __int_as_float(__builtin_amdgcn_readlane(__float_as_int(x), lane));
}

// DPP add: x + dpp_perm(x). CTRL: 0xB1=quad_perm{1,0,3,2}(xor1), 0x4E=quad_perm{2,3,0,1}(xor2),
// 0x141=row_half_mirror(pairs complementary quads), 0x140=row_mirror(pairs complementary octets).
template <int CTRL>
static __device__ __forceinline__ float dpp_add_f(float x) {
  int v = __builtin_amdgcn_update_dpp(0, __float_as_int(x), CTRL, 0xF, 0xF, true);
  return x + __int_as_float(v);
}

// sum within each 32-lane half (per-head reduce); result in every lane of the half.
static __device__ __forceinline__ float head_reduce32(float p) {
  p = dpp_add_f<0xB1>(p);
  p = dpp_add_f<0x4E>(p);
  p = dpp_add_f<0x141>(p);
  p = dpp_add_f<0x140>(p);
  p += __int_as_float(__builtin_amdgcn_ds_swizzle(__float_as_int(p), 0x401F)); // xor16
  return p;
}

// full 64-lane sum, result in every lane.
static __device__ __forceinline__ float full_reduce64(float p) {
  p = head_reduce32(p);
  p += __shfl_xor(p, 32, 64);
  return p;
}

// ======================= CSR build (counting sort by dst) =======================
__global__ void k_zero(int* __restrict__ deg, int* __restrict__ cursor, int N) {
  int i = blockIdx.x * blockDim.x + threadIdx.x;
  if (i < N) deg[i] = 0;
  if (i == 0) *cursor = 0;
}

__global__ void k_count(const int* __restrict__ ei, int* __restrict__ deg, int E) {
  int e = blockIdx.x * blockDim.x + threadIdx.x;
  if (e < E) atomicAdd(&deg[ei[E + e]], 1);
}

__global__ void k_alloc(const int* __restrict__ deg, int* __restrict__ row_off,
                        int* __restrict__ cur, int* __restrict__ cursor, int N) {
  int n = blockIdx.x * blockDim.x + threadIdx.x;
  int lane = threadIdx.x & 63;
  int d = (n < N) ? deg[n] : 0;
  int x = d;
#pragma unroll
  for (int m = 1; m <= 32; m <<= 1) {
    int t = __shfl_up(x, m, 64);
    if (lane >= m) x += t;
  }
  int wave_total = __shfl(x, 63, 64);
  int base = 0;
  if (lane == 63) base = atomicAdd(cursor, wave_total);
  base = __shfl(base, 63, 64);
  if (n < N) {
    int start = base + x - d;
    row_off[n] = start;
    cur[n] = start;
  }
}

__global__ void k_scatter(const int* __restrict__ ei, int* __restrict__ cur,
                          int* __restrict__ csr_src, int E) {
  int e = blockIdx.x * blockDim.x + threadIdx.x;
  if (e < E) {
    int d = ei[E + e];
    int p = atomicAdd(&cur[d], 1);
    csr_src[p] = ei[e];
  }
}

// ======================= k0: fold proj into layer-1 weights =======================
__global__ void k0_fuse(const float* __restrict__ projW, const float* __restrict__ projB,
                        const float* __restrict__ Wl, const float* __restrict__ Wr,
                        float* __restrict__ Wfl, float* __restrict__ Wfr,
                        float* __restrict__ bfl, float* __restrict__ bfr) {
  int t = blockIdx.x * blockDim.x + threadIdx.x;
  int total = (NDIM + 1) * HDIM;
  if (t >= total) return;
  int r = t / HDIM, c = t % HDIM;
  float al = 0.f, ar = 0.f;
  if (r < NDIM) {
    for (int k = 0; k < HDIM; ++k) {
      float w = projW[r * HDIM + k];
      al += w * Wl[k * HDIM + c];
      ar += w * Wr[k * HDIM + c];
    }
    Wfl[r * HDIM + c] = al;
    Wfr[r * HDIM + c] = ar;
  } else {
    for (int k = 0; k < HDIM; ++k) {
      float w = projB[k];
      al += w * Wl[k * HDIM + c];
      ar += w * Wr[k * HDIM + c];
    }
    bfl[c] = al;
    bfr[c] = ar;
  }
}

// ======================= k1: XL1/XR1 directly from node features =======================
__global__ void k1_xlxr(const float* __restrict__ nf, const float* __restrict__ Wfl,
                        const float* __restrict__ Wfr, const float* __restrict__ bfl,
                        const float* __restrict__ bfr, float* __restrict__ XL,
                        float* __restrict__ XR, int N) {
  int n = blockIdx.x * (blockDim.x >> 6) + (threadIdx.x >> 6);
  int j = threadIdx.x & 63;
  if (n >= N) return;
  float nfv = (j < NDIM) ? nf[n * NDIM + j] : 0.f;
  float al = bfl[j], ar = bfr[j];
#pragma unroll
  for (int k = 0; k < NDIM; ++k) {
    float xk = readlane_f(nfv, k);
    al += xk * Wfl[k * HDIM + j];
    ar += xk * Wfr[k * HDIM + j];
  }
  XL[n * HDIM + j] = al;
  XR[n * HDIM + j] = ar;
}

// ======================= k_agg: pull-aggregate + softmax + ELU + LN =======================
// wave per node; lane j = h*32+c. Zero atomics, 1 DS-op per edge.
__global__ void k_agg(const int* __restrict__ csr_src, const int* __restrict__ row_off,
                      const int* __restrict__ deg, const float* __restrict__ XL,
                      const float* __restrict__ XR, const float* __restrict__ att,
                      const float* __restrict__ gb, const float* __restrict__ lng,
                      const float* __restrict__ lnb, float* __restrict__ Y, int N) {
  int n = blockIdx.x * (blockDim.x >> 6) + (threadIdx.x >> 6);
  int j = threadIdx.x & 63;
  if (n >= N) return;
  float xr = XR[n * HDIM + j];
  float attv = att[j];

  // self-loop
  float xl = XL[n * HDIM + j];
  float p = head_reduce32(lrelu_(xl + xr) * attv);
  float ex = __expf(p);
  float acc = ex * xl;
  float den = ex;

  int base = row_off[n], cnt = deg[n];
  for (int c0 = 0; c0 < cnt; c0 += 64) {
    int m_ = cnt - c0; if (m_ > 64) m_ = 64;
    int sidx = (j < m_) ? csr_src[base + c0 + j] : 0;
    int t = 0;
    for (; t + 4 <= m_; t += 4) {
      int s0 = __builtin_amdgcn_readlane(sidx, t);
      int s1 = __builtin_amdgcn_readlane(sidx, t + 1);
      int s2 = __builtin_amdgcn_readlane(sidx, t + 2);
      int s3 = __builtin_amdgcn_readlane(sidx, t + 3);
      float x0 = XL[s0 * HDIM + j], x1 = XL[s1 * HDIM + j];
      float x2 = XL[s2 * HDIM + j], x3 = XL[s3 * HDIM + j];
      float p0 = head_reduce32(lrelu_(x0 + xr) * attv);
      float p1 = head_reduce32(lrelu_(x1 + xr) * attv);
      float p2 = head_reduce32(lrelu_(x2 + xr) * attv);
      float p3 = head_reduce32(lrelu_(x3 + xr) * attv);
      float e0 = __expf(p0), e1 = __expf(p1), e2 = __expf(p2), e3 = __expf(p3);
      acc += e0 * x0 + e1 * x1 + e2 * x2 + e3 * x3;
      den += e0 + e1 + e2 + e3;
    }
    for (; t < m_; ++t) {
      int s = __builtin_amdgcn_readlane(sidx, t);
      float xls = XL[s * HDIM + j];
      float pp = head_reduce32(lrelu_(xls + xr) * attv);
      float ee = __expf(pp);
      acc += ee * xls;
      den += ee;
    }
  }

  float y = acc / (den + 1e-16f) + gb[j];
  y = y > 0.f ? y : __expf(y) - 1.f;
  float mu = full_reduce64(y) * (1.f / 64.f);
  float d = y - mu;
  float var = full_reduce64(d * d) * (1.f / 64.f);
  Y[n * HDIM + j] = d * rsqrtf(var + 1e-5f) * lng[j] + lnb[j];
}

// ======================= k3: Y -> XL2/XR2 (persistent, 8-node batched) =======================
__global__ void __launch_bounds__(256) k3_lr(const float* __restrict__ Y,
                      const float* __restrict__ Wl, const float* __restrict__ Wr,
                      float* __restrict__ XL, float* __restrict__ XR, int N) {
  __shared__ float Wls[HDIM * HDIM];
  __shared__ float Wrs[HDIM * HDIM];
  for (int i = threadIdx.x; i < HDIM * HDIM / 4; i += blockDim.x) {
    ((float4*)Wls)[i] = ((const float4*)Wl)[i];
    ((float4*)Wrs)[i] = ((const float4*)Wr)[i];
  }
  __syncthreads();
  int wave = blockIdx.x * (blockDim.x >> 6) + (threadIdx.x >> 6);
  int nwaves = gridDim.x * (blockDim.x >> 6);
  int j = threadIdx.x & 63;
  for (int g = wave * 8; g < N; g += nwaves * 8) {
    float y[8];
#pragma unroll
    for (int i = 0; i < 8; ++i) y[i] = (g + i < N) ? Y[(g + i) * HDIM + j] : 0.f;
    float al[8], ar[8];
#pragma unroll
    for (int i = 0; i < 8; ++i) { al[i] = 0.f; ar[i] = 0.f; }
#pragma unroll
    for (int k = 0; k < HDIM; ++k) {
      float wl = Wls[k * HDIM + j];
      float wr = Wrs[k * HDIM + j];
#pragma unroll
      for (int i = 0; i < 8; ++i) {
        float xk = readlane_f(y[i], k);
        al[i] += xk * wl;
        ar[i] += xk * wr;
      }
    }
#pragma unroll
    for (int i = 0; i < 8; ++i) {
      if (g + i < N) {
        XL[(g + i) * HDIM + j] = al[i];
        XR[(g + i) * HDIM + j] = ar[i];
      }
    }
  }
}

// ======================= k5: GRU (h0=0) + 4 heads (persistent, 8-node batched) =======================
__global__ void __launch_bounds__(256) k5_gru(const float* __restrict__ Y,
                       const float* __restrict__ Wi,
                       const float* __restrict__ bi, const float* __restrict__ bh,
                       const float* __restrict__ huW, const float* __restrict__ hub,
                       const float* __restrict__ hfW, const float* __restrict__ hfb,
                       const float* __restrict__ hoW, const float* __restrict__ hob,
                       const float* __restrict__ hcW, const float* __restrict__ hcb,
                       float* __restrict__ out, int N) {
  __shared__ float Wis[HDIM * 192];
  for (int i = threadIdx.x; i < HDIM * 192 / 4; i += blockDim.x)
    ((float4*)Wis)[i] = ((const float4*)Wi)[i];
  __syncthreads();
  int wave = blockIdx.x * (blockDim.x >> 6) + (threadIdx.x >> 6);
  int nwaves = gridDim.x * (blockDim.x >> 6);
  int j = threadIdx.x & 63;
  float biR = bi[j] + bh[j], biZ = bi[64 + j] + bh[64 + j];
  float biN = bi[128 + j], bhN = bh[128 + j];
  float wu = huW[j], wf = hfW[j], wo = hoW[j], wc = hcW[j];
  float hub0 = hub[0], hfb0 = hfb[0], hob0 = hob[0], hcb0 = hcb[0];
  for (int g = wave * 8; g < N; g += nwaves * 8) {
    float y[8];
#pragma unroll
    for (int i = 0; i < 8; ++i) y[i] = (g + i < N) ? Y[(g + i) * HDIM + j] : 0.f;
    float ar[8], az[8], an[8];
#pragma unroll
    for (int i = 0; i < 8; ++i) { ar[i] = 0.f; az[i] = 0.f; an[i] = 0.f; }
#pragma unroll
    for (int k = 0; k < HDIM; ++k) {
      float wr = Wis[k * 192 + j];
      float wz = Wis[k * 192 + 64 + j];
      float wn = Wis[k * 192 + 128 + j];
#pragma unroll
      for (int i = 0; i < 8; ++i) {
        float xk = readlane_f(y[i], k);
        ar[i] += xk * wr;
        az[i] += xk * wz;
        an[i] += xk * wn;
      }
    }
#pragma unroll
    for (int i = 0; i < 8; ++i) {
      float r = sigmoidf_(ar[i] + biR);
      float z = sigmoidf_(az[i] + biZ);
      float nn = tanhf(an[i] + biN + r * bhN);
      float hv = (1.f - z) * nn;
      float pu = full_reduce64(hv * wu);
      float pf = full_reduce64(hv * wf);
      float po = full_reduce64(hv * wo);
      float pc = full_reduce64(hv * wc);
      if (j == 0 && g + i < N) {
        int n = g + i;
        out[n]         = sigmoidf_(pu + hub0);
        out[N + n]     = sigmoidf_(pf + hfb0);
        out[2 * N + n] = fmaxf(po + hob0, 0.f);
        out[3 * N + n] = sigmoidf_(pc + hcb0);
      }
    }
  }
}

// ======================= launch =======================
extern "C" void kernel_launch(void* const* d_in, const int* in_sizes, int n_in,
                              void* d_out, int out_size, void* d_ws, size_t ws_size,
                              hipStream_t stream) {
  const float* nf    = (const float*)d_in[0];
  const int*   ei    = (const int*)d_in[1];
  const float* projW = (const float*)d_in[2];
  const float* projB = (const float*)d_in[3];
  const float* g1Wl  = (const float*)d_in[4];
  const float* g1Wr  = (const float*)d_in[5];
  const float* g1att = (const float*)d_in[6];
  const float* g1b   = (const float*)d_in[7];
  const float* g2Wl  = (const float*)d_in[8];
  const float* g2Wr  = (const float*)d_in[9];
  const float* g2att = (const float*)d_in[10];
  const float* g2b   = (const float*)d_in[11];
  const float* ln1g  = (const float*)d_in[12];
  const float* ln1b  = (const float*)d_in[13];
  const float* ln2g  = (const float*)d_in[14];
  const float* ln2b  = (const float*)d_in[15];
  const float* gruWi = (const float*)d_in[16];
  // d_in[17] = gru_Wh, unused (h0 = 0)
  const float* gruBi = (const float*)d_in[18];
  const float* gruBh = (const float*)d_in[19];
  const float* huW = (const float*)d_in[20];
  const float* hub = (const float*)d_in[21];
  const float* hfW = (const float*)d_in[22];
  const float* hfb = (const float*)d_in[23];
  const float* hoW = (const float*)d_in[24];
  const float* hob = (const float*)d_in[25];
  const float* hcW = (const float*)d_in[26];
  const float* hcb = (const float*)d_in[27];
  float* out = (float*)d_out;

  const int N = in_sizes[0] / NDIM;
  const int E = in_sizes[1] / 2;

  char* ws = (char*)d_ws;
  size_t off = 0;
  auto carve = [&](size_t bytes) { void* p = ws + off; off += (bytes + 255) & ~size_t(255); return p; };
  float* XL      = (float*)carve(sizeof(float) * N * HDIM);
  float* XR      = (float*)carve(sizeof(float) * N * HDIM);
  float* Y       = (float*)carve(sizeof(float) * N * HDIM);
  int*   csr_src = (int*)carve(sizeof(int) * E);
  int*   deg     = (int*)carve(sizeof(int) * N);
  int*   row_off = (int*)carve(sizeof(int) * N);
  int*   cur     = (int*)carve(sizeof(int) * N);
  int*   cursor  = (int*)carve(sizeof(int) * 64);
  float* Wfl     = (float*)carve(sizeof(float) * NDIM * HDIM);
  float* Wfr     = (float*)carve(sizeof(float) * NDIM * HDIM);
  float* bfl     = (float*)carve(sizeof(float) * HDIM);
  float* bfr     = (float*)carve(sizeof(float) * HDIM);

  const int BLK = 256;
  dim3 b(BLK);
  dim3 gridN((N + BLK - 1) / BLK);
  dim3 gridE((E + BLK - 1) / BLK);
  dim3 gridWaveN((N + 3) / 4);   // 4 waves/block, wave per node

  // ---- CSR build ----
  k_zero<<<gridN, b, 0, stream>>>(deg, cursor, N);
  k_count<<<gridE, b, 0, stream>>>(ei, deg, E);
  k_alloc<<<gridN, b, 0, stream>>>(deg, row_off, cur, cursor, N);
  k_scatter<<<gridE, b, 0, stream>>>(ei, cur, csr_src, E);

  // ---- fold proj into layer-1 weights, then XL1/XR1 ----
  k0_fuse<<<dim3(4), b, 0, stream>>>(projW, projB, g1Wl, g1Wr, Wfl, Wfr, bfl, bfr);
  k1_xlxr<<<gridWaveN, b, 0, stream>>>(nf, Wfl, Wfr, bfl, bfr, XL, XR, N);

  // ---- GAT layer 1 (pull) ----
  k_agg<<<gridWaveN, b, 0, stream>>>(csr_src, row_off, deg, XL, XR, g1att, g1b, ln1g, ln1b, Y, N);
  // ---- layer 2 linear: persistent, 8-node batched ----
  k3_lr<<<dim3(1280), b, 0, stream>>>(Y, g2Wl, g2Wr, XL, XR, N);
  // ---- GAT layer 2 (pull) ----
  k_agg<<<gridWaveN, b, 0, stream>>>(csr_src, row_off, deg, XL, XR, g2att, g2b, ln2g, ln2b, Y, N);
  // ---- GRU + heads: persistent, 8-node batched ----
  k5_gru<<<dim3(768), b, 0, stream>>>(Y, gruWi, gruBi, gruBh,
                                      huW, hub, hfW, hfb, hoW, hob, hcW, hcb, out, N);
}

// Round 6
// 622.127 us; speedup vs baseline: 2.6331x; 1.1435x over previous
//
#include <hip/hip_runtime.h>

#define NDIM 14
#define HDIM 64
#define NB 32          // scatter buckets
#define GSTR 72        // padded LDS col stride (halfs) for GRU weights

typedef __attribute__((ext_vector_type(8))) _Float16 half8;
typedef __attribute__((ext_vector_type(4))) float f32x4;

static __device__ __forceinline__ float sigmoidf_(float x) { return 1.f / (1.f + __expf(-x)); }
static __device__ __forceinline__ float lrelu_(float x) { return x > 0.f ? x : 0.2f * x; }

static __device__ __forceinline__ float readlane_f(float x, int lane) {
  return __int_as_float(__builtin_amdgcn_readlane(__float_as_int(x), lane));
}

template <int CTRL>
static __device__ __forceinline__ float dpp_add_f(float x) {
  int v = __builtin_amdgcn_update_dpp(0, __float_as_int(x), CTRL, 0xF, 0xF, true);
  return x + __int_as_float(v);
}

// sum over each 16-lane DPP row; result in every lane of the row.
static __device__ __forceinline__ float reduce16(float p) {
  p = dpp_add_f<0xB1>(p);    // xor1 (quad_perm)
  p = dpp_add_f<0x4E>(p);    // xor2 (quad_perm)
  p = dpp_add_f<0x141>(p);   // row_half_mirror
  p = dpp_add_f<0x140>(p);   // row_mirror
  return p;
}

// sum within each 32-lane half; result in every lane of the half.
static __device__ __forceinline__ float head_reduce32(float p) {
  p = reduce16(p);
  p += __int_as_float(__builtin_amdgcn_ds_swizzle(__float_as_int(p), 0x401F)); // xor16
  return p;
}

static __device__ __forceinline__ float full_reduce64(float p) {
  p = head_reduce32(p);
  p += __shfl_xor(p, 32, 64);
  return p;
}

// ======================= CSR build =======================
__global__ void k_zero(int* __restrict__ deg, int* __restrict__ cursor,
                       int* __restrict__ hist, int N) {
  int i = blockIdx.x * blockDim.x + threadIdx.x;
  if (i < N) deg[i] = 0;
  if (i == 0) *cursor = 0;
  if (i < NB) hist[i] = 0;
}

// degree count + bucket histogram in one pass over ei
__global__ void k_counthist(const int* __restrict__ ei, int* __restrict__ deg,
                            int* __restrict__ hist, int E, int bsh) {
  __shared__ int h[NB];
  if (threadIdx.x < NB) h[threadIdx.x] = 0;
  __syncthreads();
  int e = blockIdx.x * blockDim.x + threadIdx.x;
  if (e < E) {
    int d = ei[E + e];
    atomicAdd(&deg[d], 1);
    atomicAdd(&h[d >> bsh], 1);
  }
  __syncthreads();
  if (threadIdx.x < NB && h[threadIdx.x]) atomicAdd(&hist[threadIdx.x], h[threadIdx.x]);
}

__global__ void k_alloc(const int* __restrict__ deg, int* __restrict__ row_off,
                        int* __restrict__ cur, int* __restrict__ cursor, int N) {
  int n = blockIdx.x * blockDim.x + threadIdx.x;
  int lane = threadIdx.x & 63;
  int d = (n < N) ? deg[n] : 0;
  int x = d;
#pragma unroll
  for (int m = 1; m <= 32; m <<= 1) {
    int t = __shfl_up(x, m, 64);
    if (lane >= m) x += t;
  }
  int wave_total = __shfl(x, 63, 64);
  int base = 0;
  if (lane == 63) base = atomicAdd(cursor, wave_total);
  base = __shfl(base, 63, 64);
  if (n < N) {
    int start = base + x - d;
    row_off[n] = start;
    cur[n] = start;
  }
}

__global__ void k_prefix(const int* __restrict__ hist, int* __restrict__ bucket_cur) {
  if (threadIdx.x == 0 && blockIdx.x == 0) {
    int acc = 0;
    for (int b = 0; b < NB; ++b) { bucket_cur[b] = acc; acc += hist[b]; }
  }
}

// bin edges into bucket-grouped (dst,src) pairs; block-bulk claims, coalesced-ish writes
#define EPB 16
__global__ void __launch_bounds__(256) k_bin(const int* __restrict__ ei,
                      long long* __restrict__ pairs, int* __restrict__ bucket_cur,
                      int E, int bsh) {
  __shared__ int h[NB];
  __shared__ int gb[NB];
  int t = threadIdx.x;
  if (t < NB) h[t] = 0;
  __syncthreads();
  int c0 = blockIdx.x * (256 * EPB);
  long long pr[EPB];
  int br[EPB];
#pragma unroll
  for (int i = 0; i < EPB; ++i) {
    int e = c0 + t + i * 256;
    if (e < E) {
      int s = ei[e], d = ei[E + e];
      int b = d >> bsh;
      int r = atomicAdd(&h[b], 1);
      pr[i] = ((long long)d << 32) | (unsigned)s;
      br[i] = b | (r << 6);
    } else br[i] = -1;
  }
  __syncthreads();
  if (t < NB) gb[t] = atomicAdd(&bucket_cur[t], h[t]);
  __syncthreads();
#pragma unroll
  for (int i = 0; i < EPB; ++i) {
    if (br[i] >= 0) pairs[gb[br[i] & 63] + (br[i] >> 6)] = pr[i];
  }
}

// fine scatter: consecutive threads hit the same bucket -> L2-resident csr window
__global__ void k_scatter2(const long long* __restrict__ pairs, int* __restrict__ cur,
                           int* __restrict__ csr_src, int E) {
  int i = blockIdx.x * blockDim.x + threadIdx.x;
  if (i < E) {
    long long p = pairs[i];
    int d = (int)(p >> 32);
    int s = (int)(p & 0xffffffffLL);
    int pos = atomicAdd(&cur[d], 1);
    csr_src[pos] = s;
  }
}

// ======================= k0: fold proj into layer-1 weights =======================
__global__ void k0_fuse(const float* __restrict__ projW, const float* __restrict__ projB,
                        const float* __restrict__ Wl, const float* __restrict__ Wr,
                        float* __restrict__ Wfl, float* __restrict__ Wfr,
                        float* __restrict__ bfl, float* __restrict__ bfr) {
  int t = blockIdx.x * blockDim.x + threadIdx.x;
  int total = (NDIM + 1) * HDIM;
  if (t >= total) return;
  int r = t / HDIM, c = t % HDIM;
  float al = 0.f, ar = 0.f;
  if (r < NDIM) {
    for (int k = 0; k < HDIM; ++k) {
      float w = projW[r * HDIM + k];
      al += w * Wl[k * HDIM + c];
      ar += w * Wr[k * HDIM + c];
    }
    Wfl[r * HDIM + c] = al;
    Wfr[r * HDIM + c] = ar;
  } else {
    for (int k = 0; k < HDIM; ++k) {
      float w = projB[k];
      al += w * Wl[k * HDIM + c];
      ar += w * Wr[k * HDIM + c];
    }
    bfl[c] = al;
    bfr[c] = ar;
  }
}

// ======================= k_prep: Wi f32 -> f16, col-major padded =======================
__global__ void k_prep(const float* __restrict__ Wi, _Float16* __restrict__ Wt) {
  int t = blockIdx.x * blockDim.x + threadIdx.x;
  if (t >= 192 * 64) return;
  int col = t / 64, row = t % 64;
  Wt[col * GSTR + row] = (_Float16)Wi[row * 192 + col];
}

// ======================= k1: XL1/XR1 directly from node features =======================
__global__ void k1_xlxr(const float* __restrict__ nf, const float* __restrict__ Wfl,
                        const float* __restrict__ Wfr, const float* __restrict__ bfl,
                        const float* __restrict__ bfr, float* __restrict__ XL,
                        float* __restrict__ XR, int N) {
  int n = blockIdx.x * (blockDim.x >> 6) + (threadIdx.x >> 6);
  int j = threadIdx.x & 63;
  if (n >= N) return;
  float nfv = (j < NDIM) ? nf[n * NDIM + j] : 0.f;
  float al = bfl[j], ar = bfr[j];
#pragma unroll
  for (int k = 0; k < NDIM; ++k) {
    float xk = readlane_f(nfv, k);
    al += xk * Wfl[k * HDIM + j];
    ar += xk * Wfr[k * HDIM + j];
  }
  XL[n * HDIM + j] = al;
  XR[n * HDIM + j] = ar;
}

// ======================= k_agg: pull-aggregate + softmax + ELU + LN =======================
__global__ void k_agg(const int* __restrict__ csr_src, const int* __restrict__ row_off,
                      const int* __restrict__ deg, const float* __restrict__ XL,
                      const float* __restrict__ XR, const float* __restrict__ att,
                      const float* __restrict__ gb, const float* __restrict__ lng,
                      const float* __restrict__ lnb, float* __restrict__ Y, int N) {
  int n = blockIdx.x * (blockDim.x >> 6) + (threadIdx.x >> 6);
  int j = threadIdx.x & 63;
  if (n >= N) return;
  float xr = XR[n * HDIM + j];
  float attv = att[j];

  float xl = XL[n * HDIM + j];
  float p = head_reduce32(lrelu_(xl + xr) * attv);
  float ex = __expf(p);
  float acc = ex * xl;
  float den = ex;

  int base = row_off[n], cnt = deg[n];
  for (int c0 = 0; c0 < cnt; c0 += 64) {
    int m_ = cnt - c0; if (m_ > 64) m_ = 64;
    int sidx = (j < m_) ? csr_src[base + c0 + j] : 0;
    int t = 0;
    for (; t + 8 <= m_; t += 8) {
      int s[8];
      float x[8], pp[8];
#pragma unroll
      for (int u = 0; u < 8; ++u) s[u] = __builtin_amdgcn_readlane(sidx, t + u);
#pragma unroll
      for (int u = 0; u < 8; ++u) x[u] = XL[s[u] * HDIM + j];
#pragma unroll
      for (int u = 0; u < 8; ++u) pp[u] = head_reduce32(lrelu_(x[u] + xr) * attv);
#pragma unroll
      for (int u = 0; u < 8; ++u) {
        float ee = __expf(pp[u]);
        acc += ee * x[u];
        den += ee;
      }
    }
    for (; t < m_; ++t) {
      int s = __builtin_amdgcn_readlane(sidx, t);
      float xls = XL[s * HDIM + j];
      float pq = head_reduce32(lrelu_(xls + xr) * attv);
      float ee = __expf(pq);
      acc += ee * xls;
      den += ee;
    }
  }

  float y = acc / (den + 1e-16f) + gb[j];
  y = y > 0.f ? y : __expf(y) - 1.f;
  float mu = full_reduce64(y) * (1.f / 64.f);
  float d = y - mu;
  float var = full_reduce64(d * d) * (1.f / 64.f);
  Y[n * HDIM + j] = d * rsqrtf(var + 1e-5f) * lng[j] + lnb[j];
}

// ======================= k3: Y -> XL2/XR2 (persistent, 8-node batched, fp32) =======================
__global__ void __launch_bounds__(256) k3_lr(const float* __restrict__ Y,
                      const float* __restrict__ Wl, const float* __restrict__ Wr,
                      float* __restrict__ XL, float* __restrict__ XR, int N) {
  __shared__ float Wls[HDIM * HDIM];
  __shared__ float Wrs[HDIM * HDIM];
  for (int i = threadIdx.x; i < HDIM * HDIM / 4; i += blockDim.x) {
    ((float4*)Wls)[i] = ((const float4*)Wl)[i];
    ((float4*)Wrs)[i] = ((const float4*)Wr)[i];
  }
  __syncthreads();
  int wave = blockIdx.x * (blockDim.x >> 6) + (threadIdx.x >> 6);
  int nwaves = gridDim.x * (blockDim.x >> 6);
  int j = threadIdx.x & 63;
  for (int g = wave * 8; g < N; g += nwaves * 8) {
    float y[8];
#pragma unroll
    for (int i = 0; i < 8; ++i) y[i] = (g + i < N) ? Y[(g + i) * HDIM + j] : 0.f;
    float al[8], ar[8];
#pragma unroll
    for (int i = 0; i < 8; ++i) { al[i] = 0.f; ar[i] = 0.f; }
#pragma unroll
    for (int k = 0; k < HDIM; ++k) {
      float wl = Wls[k * HDIM + j];
      float wr = Wrs[k * HDIM + j];
#pragma unroll
      for (int i = 0; i < 8; ++i) {
        float xk = readlane_f(y[i], k);
        al[i] += xk * wl;
        ar[i] += xk * wr;
      }
    }
#pragma unroll
    for (int i = 0; i < 8; ++i) {
      if (g + i < N) {
        XL[(g + i) * HDIM + j] = al[i];
        XR[(g + i) * HDIM + j] = ar[i];
      }
    }
  }
}

// ======================= k5: GRU via f16 MFMA + heads =======================
// Wave computes 16 nodes: G[16x192] = Y[16x64] @ Wi[64x192] as 12 col-tiles x 2 K-halves.
// C/D layout: col=lane&15, row=(lane>>4)*4+reg  [m89]. A: row=lane&15, k=(lane>>4)*8+i. B: col=lane&15, k=(lane>>4)*8+i.
__global__ void __launch_bounds__(256) k5_gru_mfma(const float* __restrict__ Y,
                       const _Float16* __restrict__ Wt,
                       const float* __restrict__ bi, const float* __restrict__ bh,
                       const float* __restrict__ huW, const float* __restrict__ hub,
                       const float* __restrict__ hfW, const float* __restrict__ hfb,
                       const float* __restrict__ hoW, const float* __restrict__ hob,
                       const float* __restrict__ hcW, const float* __restrict__ hcb,
                       float* __restrict__ out, int N) {
  __shared__ _Float16 W[192 * GSTR];
  __shared__ float BS[192];
  __shared__ float BHN[64];
  for (int i = threadIdx.x; i < 192 * GSTR / 8; i += 256)
    ((int4*)W)[i] = ((const int4*)Wt)[i];
  for (int i = threadIdx.x; i < 192; i += 256) BS[i] = bi[i] + (i < 128 ? bh[i] : 0.f);
  for (int i = threadIdx.x; i < 64; i += 256) BHN[i] = bh[128 + i];
  __syncthreads();

  int wave = blockIdx.x * 4 + (threadIdx.x >> 6);
  int nwaves = gridDim.x * 4;
  int lane = threadIdx.x & 63;
  int c = lane & 15, q = lane >> 4;

  float hu_[4], hf_[4], ho_[4], hc_[4];
#pragma unroll
  for (int t = 0; t < 4; ++t) {
    hu_[t] = huW[t * 16 + c];
    hf_[t] = hfW[t * 16 + c];
    ho_[t] = hoW[t * 16 + c];
    hc_[t] = hcW[t * 16 + c];
  }
  float hub0 = hub[0], hfb0 = hfb[0], hob0 = hob[0], hcb0 = hcb[0];

  for (int n0 = wave * 16; n0 < N; n0 += nwaves * 16) {
    // A fragments (f32 -> f16)
    bool okrow = (n0 + c) < N;
    const float* yrow = Y + (size_t)(n0 + c) * HDIM + q * 8;
    float4 v0 = {0,0,0,0}, v1 = {0,0,0,0}, v2 = {0,0,0,0}, v3 = {0,0,0,0};
    if (okrow) {
      v0 = *(const float4*)(yrow);
      v1 = *(const float4*)(yrow + 4);
      v2 = *(const float4*)(yrow + 32);
      v3 = *(const float4*)(yrow + 36);
    }
    half8 a0, a1;
    a0[0] = (_Float16)v0.x; a0[1] = (_Float16)v0.y; a0[2] = (_Float16)v0.z; a0[3] = (_Float16)v0.w;
    a0[4] = (_Float16)v1.x; a0[5] = (_Float16)v1.y; a0[6] = (_Float16)v1.z; a0[7] = (_Float16)v1.w;
    a1[0] = (_Float16)v2.x; a1[1] = (_Float16)v2.y; a1[2] = (_Float16)v2.z; a1[3] = (_Float16)v2.w;
    a1[4] = (_Float16)v3.x; a1[5] = (_Float16)v3.y; a1[6] = (_Float16)v3.z; a1[7] = (_Float16)v3.w;

    f32x4 acc[12];
#pragma unroll
    for (int t = 0; t < 12; ++t) acc[t] = (f32x4){0.f, 0.f, 0.f, 0.f};
#pragma unroll
    for (int t = 0; t < 12; ++t) {
      half8 b0 = *(const half8*)(&W[(t * 16 + c) * GSTR + q * 8]);
      half8 b1 = *(const half8*)(&W[(t * 16 + c) * GSTR + 32 + q * 8]);
      acc[t] = __builtin_amdgcn_mfma_f32_16x16x32_f16(a0, b0, acc[t], 0, 0, 0);
      acc[t] = __builtin_amdgcn_mfma_f32_16x16x32_f16(a1, b1, acc[t], 0, 0, 0);
    }

    // GRU elementwise in fragment layout: cols t*16+c; t:0..3=r, 4..7=z, 8..11=n
    float hv[4][4];
#pragma unroll
    for (int t = 0; t < 4; ++t) {
      int cr = t * 16 + c;
      float bsr = BS[cr], bsz = BS[64 + cr], bsn = BS[128 + cr], bhn = BHN[cr];
#pragma unroll
      for (int i = 0; i < 4; ++i) {
        float r = sigmoidf_(acc[t][i] + bsr);
        float z = sigmoidf_(acc[t + 4][i] + bsz);
        float nn = tanhf(acc[t + 8][i] + bsn + r * bhn);
        hv[t][i] = (1.f - z) * nn;
      }
    }
    // heads: per row (q*4+i) reduce over 16 lanes (c)
#pragma unroll
    for (int i = 0; i < 4; ++i) {
      float pu = 0.f, pf = 0.f, po = 0.f, pc = 0.f;
#pragma unroll
      for (int t = 0; t < 4; ++t) {
        pu += hv[t][i] * hu_[t];
        pf += hv[t][i] * hf_[t];
        po += hv[t][i] * ho_[t];
        pc += hv[t][i] * hc_[t];
      }
      pu = reduce16(pu); pf = reduce16(pf); po = reduce16(po); pc = reduce16(pc);
      int n = n0 + q * 4 + i;
      if (n < N) {
        if (c == 0) out[n]         = sigmoidf_(pu + hub0);
        if (c == 1) out[N + n]     = sigmoidf_(pf + hfb0);
        if (c == 2) out[2 * N + n] = fmaxf(po + hob0, 0.f);
        if (c == 3) out[3 * N + n] = sigmoidf_(pc + hcb0);
      }
    }
  }
}

// ======================= launch =======================
extern "C" void kernel_launch(void* const* d_in, const int* in_sizes, int n_in,
                              void* d_out, int out_size, void* d_ws, size_t ws_size,
                              hipStream_t stream) {
  const float* nf    = (const float*)d_in[0];
  const int*   ei    = (const int*)d_in[1];
  const float* projW = (const float*)d_in[2];
  const float* projB = (const float*)d_in[3];
  const float* g1Wl  = (const float*)d_in[4];
  const float* g1Wr  = (const float*)d_in[5];
  const float* g1att = (const float*)d_in[6];
  const float* g1b   = (const float*)d_in[7];
  const float* g2Wl  = (const float*)d_in[8];
  const float* g2Wr  = (const float*)d_in[9];
  const float* g2att = (const float*)d_in[10];
  const float* g2b   = (const float*)d_in[11];
  const float* ln1g  = (const float*)d_in[12];
  const float* ln1b  = (const float*)d_in[13];
  const float* ln2g  = (const float*)d_in[14];
  const float* ln2b  = (const float*)d_in[15];
  const float* gruWi = (const float*)d_in[16];
  // d_in[17] = gru_Wh, unused (h0 = 0)
  const float* gruBi = (const float*)d_in[18];
  const float* gruBh = (const float*)d_in[19];
  const float* huW = (const float*)d_in[20];
  const float* hub = (const float*)d_in[21];
  const float* hfW = (const float*)d_in[22];
  const float* hfb = (const float*)d_in[23];
  const float* hoW = (const float*)d_in[24];
  const float* hob = (const float*)d_in[25];
  const float* hcW = (const float*)d_in[26];
  const float* hcb = (const float*)d_in[27];
  float* out = (float*)d_out;

  const int N = in_sizes[0] / NDIM;
  const int E = in_sizes[1] / 2;
  int bsh = 12;
  while ((N >> bsh) >= NB) ++bsh;

  char* ws = (char*)d_ws;
  size_t off = 0;
  auto carve = [&](size_t bytes) { void* p = ws + off; off += (bytes + 255) & ~size_t(255); return p; };
  float*     XL      = (float*)carve(sizeof(float) * N * HDIM);
  float*     XR      = (float*)carve(sizeof(float) * N * HDIM);
  float*     Y       = (float*)carve(sizeof(float) * N * HDIM);
  long long* pairs   = (long long*)carve(sizeof(long long) * E);
  int*       csr_src = (int*)carve(sizeof(int) * E);
  int*       deg     = (int*)carve(sizeof(int) * N);
  int*       row_off = (int*)carve(sizeof(int) * N);
  int*       cur     = (int*)carve(sizeof(int) * N);
  int*       cursor  = (int*)carve(sizeof(int) * 64);
  int*       hist    = (int*)carve(sizeof(int) * NB);
  int*       bcur    = (int*)carve(sizeof(int) * NB);
  float*     Wfl     = (float*)carve(sizeof(float) * NDIM * HDIM);
  float*     Wfr     = (float*)carve(sizeof(float) * NDIM * HDIM);
  float*     bfl     = (float*)carve(sizeof(float) * HDIM);
  float*     bfr     = (float*)carve(sizeof(float) * HDIM);
  _Float16*  Wt      = (_Float16*)carve(sizeof(_Float16) * 192 * GSTR);

  const int BLK = 256;
  dim3 b(BLK);
  dim3 gridN((N + BLK - 1) / BLK);
  dim3 gridE((E + BLK - 1) / BLK);
  dim3 gridWaveN((N + 3) / 4);
  dim3 gridBin((E + BLK * EPB - 1) / (BLK * EPB));

  // ---- CSR build (binned two-phase scatter) ----
  k_zero<<<gridN, b, 0, stream>>>(deg, cursor, hist, N);
  k_counthist<<<gridE, b, 0, stream>>>(ei, deg, hist, E, bsh);
  k_alloc<<<gridN, b, 0, stream>>>(deg, row_off, cur, cursor, N);
  k_prefix<<<dim3(1), dim3(64), 0, stream>>>(hist, bcur);
  k_bin<<<gridBin, b, 0, stream>>>(ei, pairs, bcur, E, bsh);
  k_scatter2<<<gridE, b, 0, stream>>>(pairs, cur, csr_src, E);

  // ---- weight prep ----
  k0_fuse<<<dim3(4), b, 0, stream>>>(projW, projB, g1Wl, g1Wr, Wfl, Wfr, bfl, bfr);
  k_prep<<<dim3(48), b, 0, stream>>>(gruWi, Wt);

  // ---- pipeline ----
  k1_xlxr<<<gridWaveN, b, 0, stream>>>(nf, Wfl, Wfr, bfl, bfr, XL, XR, N);
  k_agg<<<gridWaveN, b, 0, stream>>>(csr_src, row_off, deg, XL, XR, g1att, g1b, ln1g, ln1b, Y, N);
  k3_lr<<<dim3(1280), b, 0, stream>>>(Y, g2Wl, g2Wr, XL, XR, N);
  k_agg<<<gridWaveN, b, 0, stream>>>(csr_src, row_off, deg, XL, XR, g2att, g2b, ln2g, ln2b, Y, N);
  k5_gru_mfma<<<dim3(800), b, 0, stream>>>(Y, Wt, gruBi, gruBh,
                                           huW, hub, hfW, hfb, hoW, hob, hcW, hcb, out, N);
}

// Round 7
// 457.594 us; speedup vs baseline: 3.5799x; 1.3596x over previous
//
#include <hip/hip_runtime.h>

#define NDIM 14
#define HDIM 64
#define NB 512         // scatter buckets (node range = 1<<bsh, bsh=8 for N<=131072)
#define EPB 16         // edges per thread in k_bin
#define GSTR 72        // padded col stride (halfs) for GRU weights

typedef __attribute__((ext_vector_type(8))) _Float16 half8;
typedef __attribute__((ext_vector_type(4))) float f32x4;

static __device__ __forceinline__ float sigmoidf_(float x) { return 1.f / (1.f + __expf(-x)); }
static __device__ __forceinline__ float lrelu_(float x) { return x > 0.f ? x : 0.2f * x; }

static __device__ __forceinline__ float readlane_f(float x, int lane) {
  return __int_as_float(__builtin_amdgcn_readlane(__float_as_int(x), lane));
}

template <int CTRL>
static __device__ __forceinline__ float dpp_add_f(float x) {
  int v = __builtin_amdgcn_update_dpp(0, __float_as_int(x), CTRL, 0xF, 0xF, true);
  return x + __int_as_float(v);
}

// sum over each 16-lane DPP row; result in every lane of the row.
static __device__ __forceinline__ float reduce16(float p) {
  p = dpp_add_f<0xB1>(p);    // xor1
  p = dpp_add_f<0x4E>(p);    // xor2
  p = dpp_add_f<0x141>(p);   // row_half_mirror
  p = dpp_add_f<0x140>(p);   // row_mirror
  return p;
}

static __device__ __forceinline__ float head_reduce32(float p) {
  p = reduce16(p);
  p += __int_as_float(__builtin_amdgcn_ds_swizzle(__float_as_int(p), 0x401F)); // xor16
  return p;
}

static __device__ __forceinline__ float full_reduce64(float p) {
  p = head_reduce32(p);
  p += __shfl_xor(p, 32, 64);
  return p;
}

// ======================= CSR build (bucket-first, LDS-local) =======================
// 1) bucket histogram (LDS only; no per-node atomics)
__global__ void k_hist(const int* __restrict__ dst, int* __restrict__ hist, int E, int bsh) {
  __shared__ int h[NB];
  for (int i = threadIdx.x; i < NB; i += 256) h[i] = 0;
  __syncthreads();
  for (int e = blockIdx.x * 256 + threadIdx.x; e < E; e += gridDim.x * 256)
    atomicAdd(&h[dst[e] >> bsh], 1);
  __syncthreads();
  for (int i = threadIdx.x; i < NB; i += 256)
    if (h[i]) atomicAdd(&hist[i], h[i]);
}

// 2) bucket prefix -> bases
__global__ void k_prefix(const int* __restrict__ hist, int* __restrict__ base,
                         int* __restrict__ bcur) {
  if (threadIdx.x == 0 && blockIdx.x == 0) {
    int acc = 0;
    for (int b = 0; b < NB; ++b) { base[b] = acc; bcur[b] = acc; acc += hist[b]; }
    base[NB] = acc;
  }
}

// 3) bin edges into bucket-grouped (dst,src) pairs
__global__ void __launch_bounds__(256) k_bin(const int* __restrict__ ei,
                      long long* __restrict__ pairs, int* __restrict__ bucket_cur,
                      int E, int bsh) {
  __shared__ int h[NB];
  __shared__ int gb[NB];
  int t = threadIdx.x;
  for (int i = t; i < NB; i += 256) h[i] = 0;
  __syncthreads();
  int c0 = blockIdx.x * (256 * EPB);
  long long pr[EPB];
  int br[EPB];
#pragma unroll
  for (int i = 0; i < EPB; ++i) {
    int e = c0 + t + i * 256;
    if (e < E) {
      int s = ei[e], d = ei[E + e];
      int b = d >> bsh;
      int r = atomicAdd(&h[b], 1);
      pr[i] = ((long long)d << 32) | (unsigned)s;
      br[i] = b | (r << 9);
    } else br[i] = -1;
  }
  __syncthreads();
  for (int i = t; i < NB; i += 256)
    if (h[i]) gb[i] = atomicAdd(&bucket_cur[i], h[i]);
  __syncthreads();
#pragma unroll
  for (int i = 0; i < EPB; ++i) {
    if (br[i] >= 0) pairs[gb[br[i] & (NB - 1)] + (br[i] >> 9)] = pr[i];
  }
}

// 4) per-bucket CSR: degree hist + scan + placement, all in LDS. One block per bucket.
__global__ void __launch_bounds__(256) k_csr(const long long* __restrict__ pairs,
                      const int* __restrict__ base, int* __restrict__ row_off,
                      int* __restrict__ deg, int* __restrict__ csr_src, int N, int bsh) {
  __shared__ int h[1024];
  __shared__ int cu[1024];
  __shared__ int wtot[4];
  int b = blockIdx.x;
  int node0 = b << bsh;
  int range = 1 << bsh;
  int nr = N - node0; if (nr > range) nr = range;
  if (nr <= 0) return;
  int e0 = base[b], e1 = base[b + 1];
  int tid = threadIdx.x;
  for (int i = tid; i < range; i += 256) h[i] = 0;
  __syncthreads();
  for (int e = e0 + tid; e < e1; e += 256)
    atomicAdd(&h[(int)(pairs[e] >> 32) - node0], 1);
  __syncthreads();
  if (range == 256) {           // fast parallel scan (N<=131072 path)
    int lane = tid & 63, wid = tid >> 6;
    int v = (tid < nr) ? h[tid] : 0;
    int x = v;
#pragma unroll
    for (int m = 1; m <= 32; m <<= 1) {
      int t2 = __shfl_up(x, m, 64);
      if (lane >= m) x += t2;
    }
    if (lane == 63) wtot[wid] = x;
    __syncthreads();
    int woff = 0;
#pragma unroll
    for (int w = 0; w < 4; ++w) woff += (w < wid) ? wtot[w] : 0;
    int excl = woff + x - v;
    if (tid < nr) {
      row_off[node0 + tid] = e0 + excl;
      deg[node0 + tid] = v;
      cu[tid] = excl;
    }
  } else {                      // generic fallback
    if (tid == 0) {
      int acc = 0;
      for (int i = 0; i < nr; ++i) {
        row_off[node0 + i] = e0 + acc;
        deg[node0 + i] = h[i];
        cu[i] = acc;
        acc += h[i];
      }
    }
  }
  __syncthreads();
  for (int e = e0 + tid; e < e1; e += 256) {
    long long pk = pairs[e];
    int d = (int)(pk >> 32), s = (int)pk;
    int p = atomicAdd(&cu[d - node0], 1);
    csr_src[e0 + p] = s;
  }
}

// ======================= k0: fold proj into layer-1 weights =======================
__global__ void k0_fuse(const float* __restrict__ projW, const float* __restrict__ projB,
                        const float* __restrict__ Wl, const float* __restrict__ Wr,
                        float* __restrict__ Wfl, float* __restrict__ Wfr,
                        float* __restrict__ bfl, float* __restrict__ bfr) {
  int t = blockIdx.x * blockDim.x + threadIdx.x;
  int total = (NDIM + 1) * HDIM;
  if (t >= total) return;
  int r = t / HDIM, c = t % HDIM;
  float al = 0.f, ar = 0.f;
  if (r < NDIM) {
    for (int k = 0; k < HDIM; ++k) {
      float w = projW[r * HDIM + k];
      al += w * Wl[k * HDIM + c];
      ar += w * Wr[k * HDIM + c];
    }
    Wfl[r * HDIM + c] = al;
    Wfr[r * HDIM + c] = ar;
  } else {
    for (int k = 0; k < HDIM; ++k) {
      float w = projB[k];
      al += w * Wl[k * HDIM + c];
      ar += w * Wr[k * HDIM + c];
    }
    bfl[c] = al;
    bfr[c] = ar;
  }
}

// ======================= k_prep: Wi f32 -> f16, col-major padded =======================
__global__ void k_prep(const float* __restrict__ Wi, _Float16* __restrict__ Wt) {
  int t = blockIdx.x * blockDim.x + threadIdx.x;
  if (t >= 192 * 64) return;
  int col = t / 64, row = t % 64;
  Wt[col * GSTR + row] = (_Float16)Wi[row * 192 + col];
}

// ======================= k1: XL1/XR1 directly from node features =======================
__global__ void k1_xlxr(const float* __restrict__ nf, const float* __restrict__ Wfl,
                        const float* __restrict__ Wfr, const float* __restrict__ bfl,
                        const float* __restrict__ bfr, float* __restrict__ XL,
                        float* __restrict__ XR, int N) {
  int n = blockIdx.x * (blockDim.x >> 6) + (threadIdx.x >> 6);
  int j = threadIdx.x & 63;
  if (n >= N) return;
  float nfv = (j < NDIM) ? nf[n * NDIM + j] : 0.f;
  float al = bfl[j], ar = bfr[j];
#pragma unroll
  for (int k = 0; k < NDIM; ++k) {
    float xk = readlane_f(nfv, k);
    al += xk * Wfl[k * HDIM + j];
    ar += xk * Wfr[k * HDIM + j];
  }
  XL[n * HDIM + j] = al;
  XR[n * HDIM + j] = ar;
}

// ======================= k_agg: pull-aggregate + softmax + ELU + LN =======================
// wave per node; lane j = h*32+c. Masked 8-batches + ping-pong prefetch.
#define LOAD8(buf, toff)                                        \
  do {                                                          \
    _Pragma("unroll") for (int u = 0; u < 8; ++u) {             \
      int s = __builtin_amdgcn_readlane(sidx, (toff) + u);      \
      buf[u] = XL[(size_t)s * HDIM + j];                        \
    }                                                           \
  } while (0)

#define PROC8(buf, toff)                                        \
  do {                                                          \
    _Pragma("unroll") for (int u = 0; u < 8; ++u) {             \
      float pp = head_reduce32(lrelu_(buf[u] + xr) * attv);     \
      float ee = __expf(pp);                                    \
      ee = ((toff) + u < m_) ? ee : 0.f;                        \
      acc += ee * buf[u];                                       \
      den += ee;                                                \
    }                                                           \
  } while (0)

__global__ void k_agg(const int* __restrict__ csr_src, const int* __restrict__ row_off,
                      const int* __restrict__ deg, const float* __restrict__ XL,
                      const float* __restrict__ XR, const float* __restrict__ att,
                      const float* __restrict__ gb, const float* __restrict__ lng,
                      const float* __restrict__ lnb, float* __restrict__ Y, int N) {
  int n = blockIdx.x * (blockDim.x >> 6) + (threadIdx.x >> 6);
  int j = threadIdx.x & 63;
  if (n >= N) return;
  float xr = XR[n * HDIM + j];
  float attv = att[j];

  float xl = XL[n * HDIM + j];
  float p = head_reduce32(lrelu_(xl + xr) * attv);
  float ex = __expf(p);
  float acc = ex * xl;
  float den = ex;

  int base = row_off[n], cnt = deg[n];
  for (int c0 = 0; c0 < cnt; c0 += 64) {
    int m_ = cnt - c0; if (m_ > 64) m_ = 64;
    int sidx = (j < m_) ? csr_src[base + c0 + j] : 0;
    int nb = (m_ + 7) >> 3;
    float xa[8], xb[8];
    LOAD8(xa, 0);
    for (int t = 0; t < nb; t += 2) {
      if (t + 1 < nb) LOAD8(xb, (t + 1) * 8);
      PROC8(xa, t * 8);
      if (t + 1 < nb) {
        if (t + 2 < nb) LOAD8(xa, (t + 2) * 8);
        PROC8(xb, (t + 1) * 8);
      }
    }
  }

  float y = acc / (den + 1e-16f) + gb[j];
  y = y > 0.f ? y : __expf(y) - 1.f;
  float mu = full_reduce64(y) * (1.f / 64.f);
  float d = y - mu;
  float var = full_reduce64(d * d) * (1.f / 64.f);
  Y[n * HDIM + j] = d * rsqrtf(var + 1e-5f) * lng[j] + lnb[j];
}

// ======================= k3: Y -> XL2/XR2 (persistent, 8-node batched, fp32) =======================
__global__ void __launch_bounds__(256) k3_lr(const float* __restrict__ Y,
                      const float* __restrict__ Wl, const float* __restrict__ Wr,
                      float* __restrict__ XL, float* __restrict__ XR, int N) {
  __shared__ float Wls[HDIM * HDIM];
  __shared__ float Wrs[HDIM * HDIM];
  for (int i = threadIdx.x; i < HDIM * HDIM / 4; i += blockDim.x) {
    ((float4*)Wls)[i] = ((const float4*)Wl)[i];
    ((float4*)Wrs)[i] = ((const float4*)Wr)[i];
  }
  __syncthreads();
  int wave = blockIdx.x * (blockDim.x >> 6) + (threadIdx.x >> 6);
  int nwaves = gridDim.x * (blockDim.x >> 6);
  int j = threadIdx.x & 63;
  for (int g = wave * 8; g < N; g += nwaves * 8) {
    float y[8];
#pragma unroll
    for (int i = 0; i < 8; ++i) y[i] = (g + i < N) ? Y[(g + i) * HDIM + j] : 0.f;
    float al[8], ar[8];
#pragma unroll
    for (int i = 0; i < 8; ++i) { al[i] = 0.f; ar[i] = 0.f; }
#pragma unroll
    for (int k = 0; k < HDIM; ++k) {
      float wl = Wls[k * HDIM + j];
      float wr = Wrs[k * HDIM + j];
#pragma unroll
      for (int i = 0; i < 8; ++i) {
        float xk = readlane_f(y[i], k);
        al[i] += xk * wl;
        ar[i] += xk * wr;
      }
    }
#pragma unroll
    for (int i = 0; i < 8; ++i) {
      if (g + i < N) {
        XL[(g + i) * HDIM + j] = al[i];
        XR[(g + i) * HDIM + j] = ar[i];
      }
    }
  }
}

// ======================= k5: GRU via f16 MFMA + heads =======================
__global__ void __launch_bounds__(256) k5_gru_mfma(const float* __restrict__ Y,
                       const _Float16* __restrict__ Wt,
                       const float* __restrict__ bi, const float* __restrict__ bh,
                       const float* __restrict__ huW, const float* __restrict__ hub,
                       const float* __restrict__ hfW, const float* __restrict__ hfb,
                       const float* __restrict__ hoW, const float* __restrict__ hob,
                       const float* __restrict__ hcW, const float* __restrict__ hcb,
                       float* __restrict__ out, int N) {
  __shared__ _Float16 W[192 * GSTR];
  __shared__ float BS[192];
  __shared__ float BHN[64];
  for (int i = threadIdx.x; i < 192 * GSTR / 8; i += 256)
    ((int4*)W)[i] = ((const int4*)Wt)[i];
  for (int i = threadIdx.x; i < 192; i += 256) BS[i] = bi[i] + (i < 128 ? bh[i] : 0.f);
  for (int i = threadIdx.x; i < 64; i += 256) BHN[i] = bh[128 + i];
  __syncthreads();

  int wave = blockIdx.x * 4 + (threadIdx.x >> 6);
  int nwaves = gridDim.x * 4;
  int lane = threadIdx.x & 63;
  int c = lane & 15, q = lane >> 4;

  float hu_[4], hf_[4], ho_[4], hc_[4];
#pragma unroll
  for (int t = 0; t < 4; ++t) {
    hu_[t] = huW[t * 16 + c];
    hf_[t] = hfW[t * 16 + c];
    ho_[t] = hoW[t * 16 + c];
    hc_[t] = hcW[t * 16 + c];
  }
  float hub0 = hub[0], hfb0 = hfb[0], hob0 = hob[0], hcb0 = hcb[0];

  for (int n0 = wave * 16; n0 < N; n0 += nwaves * 16) {
    bool okrow = (n0 + c) < N;
    const float* yrow = Y + (size_t)(n0 + c) * HDIM + q * 8;
    float4 v0 = {0,0,0,0}, v1 = {0,0,0,0}, v2 = {0,0,0,0}, v3 = {0,0,0,0};
    if (okrow) {
      v0 = *(const float4*)(yrow);
      v1 = *(const float4*)(yrow + 4);
      v2 = *(const float4*)(yrow + 32);
      v3 = *(const float4*)(yrow + 36);
    }
    half8 a0, a1;
    a0[0] = (_Float16)v0.x; a0[1] = (_Float16)v0.y; a0[2] = (_Float16)v0.z; a0[3] = (_Float16)v0.w;
    a0[4] = (_Float16)v1.x; a0[5] = (_Float16)v1.y; a0[6] = (_Float16)v1.z; a0[7] = (_Float16)v1.w;
    a1[0] = (_Float16)v2.x; a1[1] = (_Float16)v2.y; a1[2] = (_Float16)v2.z; a1[3] = (_Float16)v2.w;
    a1[4] = (_Float16)v3.x; a1[5] = (_Float16)v3.y; a1[6] = (_Float16)v3.z; a1[7] = (_Float16)v3.w;

    f32x4 acc[12];
#pragma unroll
    for (int t = 0; t < 12; ++t) acc[t] = (f32x4){0.f, 0.f, 0.f, 0.f};
#pragma unroll
    for (int t = 0; t < 12; ++t) {
      half8 b0 = *(const half8*)(&W[(t * 16 + c) * GSTR + q * 8]);
      half8 b1 = *(const half8*)(&W[(t * 16 + c) * GSTR + 32 + q * 8]);
      acc[t] = __builtin_amdgcn_mfma_f32_16x16x32_f16(a0, b0, acc[t], 0, 0, 0);
      acc[t] = __builtin_amdgcn_mfma_f32_16x16x32_f16(a1, b1, acc[t], 0, 0, 0);
    }

    float hv[4][4];
#pragma unroll
    for (int t = 0; t < 4; ++t) {
      int cr = t * 16 + c;
      float bsr = BS[cr], bsz = BS[64 + cr], bsn = BS[128 + cr], bhn = BHN[cr];
#pragma unroll
      for (int i = 0; i < 4; ++i) {
        float r = sigmoidf_(acc[t][i] + bsr);
        float z = sigmoidf_(acc[t + 4][i] + bsz);
        float nn = tanhf(acc[t + 8][i] + bsn + r * bhn);
        hv[t][i] = (1.f - z) * nn;
      }
    }
#pragma unroll
    for (int i = 0; i < 4; ++i) {
      float pu = 0.f, pf = 0.f, po = 0.f, pc = 0.f;
#pragma unroll
      for (int t = 0; t < 4; ++t) {
        pu += hv[t][i] * hu_[t];
        pf += hv[t][i] * hf_[t];
        po += hv[t][i] * ho_[t];
        pc += hv[t][i] * hc_[t];
      }
      pu = reduce16(pu); pf = reduce16(pf); po = reduce16(po); pc = reduce16(pc);
      int n = n0 + q * 4 + i;
      if (n < N) {
        if (c == 0) out[n]         = sigmoidf_(pu + hub0);
        if (c == 1) out[N + n]     = sigmoidf_(pf + hfb0);
        if (c == 2) out[2 * N + n] = fmaxf(po + hob0, 0.f);
        if (c == 3) out[3 * N + n] = sigmoidf_(pc + hcb0);
      }
    }
  }
}

// ======================= launch =======================
extern "C" void kernel_launch(void* const* d_in, const int* in_sizes, int n_in,
                              void* d_out, int out_size, void* d_ws, size_t ws_size,
                              hipStream_t stream) {
  const float* nf    = (const float*)d_in[0];
  const int*   ei    = (const int*)d_in[1];
  const float* projW = (const float*)d_in[2];
  const float* projB = (const float*)d_in[3];
  const float* g1Wl  = (const float*)d_in[4];
  const float* g1Wr  = (const float*)d_in[5];
  const float* g1att = (const float*)d_in[6];
  const float* g1b   = (const float*)d_in[7];
  const float* g2Wl  = (const float*)d_in[8];
  const float* g2Wr  = (const float*)d_in[9];
  const float* g2att = (const float*)d_in[10];
  const float* g2b   = (const float*)d_in[11];
  const float* ln1g  = (const float*)d_in[12];
  const float* ln1b  = (const float*)d_in[13];
  const float* ln2g  = (const float*)d_in[14];
  const float* ln2b  = (const float*)d_in[15];
  const float* gruWi = (const float*)d_in[16];
  // d_in[17] = gru_Wh, unused (h0 = 0)
  const float* gruBi = (const float*)d_in[18];
  const float* gruBh = (const float*)d_in[19];
  const float* huW = (const float*)d_in[20];
  const float* hub = (const float*)d_in[21];
  const float* hfW = (const float*)d_in[22];
  const float* hfb = (const float*)d_in[23];
  const float* hoW = (const float*)d_in[24];
  const float* hob = (const float*)d_in[25];
  const float* hcW = (const float*)d_in[26];
  const float* hcb = (const float*)d_in[27];
  float* out = (float*)d_out;

  const int N = in_sizes[0] / NDIM;
  const int E = in_sizes[1] / 2;
  int bsh = 8;
  while (((N - 1) >> bsh) >= NB) ++bsh;
  const int nbu = (N + (1 << bsh) - 1) >> bsh;   // used buckets

  char* ws = (char*)d_ws;
  size_t off = 0;
  auto carve = [&](size_t bytes) { void* p = ws + off; off += (bytes + 255) & ~size_t(255); return p; };
  float*     XL      = (float*)carve(sizeof(float) * N * HDIM);
  float*     XR      = (float*)carve(sizeof(float) * N * HDIM);
  float*     Y       = (float*)carve(sizeof(float) * N * HDIM);
  long long* pairs   = (long long*)carve(sizeof(long long) * E);
  int*       csr_src = (int*)carve(sizeof(int) * E);
  int*       deg     = (int*)carve(sizeof(int) * N);
  int*       row_off = (int*)carve(sizeof(int) * N);
  int*       hist    = (int*)carve(sizeof(int) * NB);
  int*       bbase   = (int*)carve(sizeof(int) * (NB + 1));
  int*       bcur    = (int*)carve(sizeof(int) * NB);
  float*     Wfl     = (float*)carve(sizeof(float) * NDIM * HDIM);
  float*     Wfr     = (float*)carve(sizeof(float) * NDIM * HDIM);
  float*     bfl     = (float*)carve(sizeof(float) * HDIM);
  float*     bfr     = (float*)carve(sizeof(float) * HDIM);
  _Float16*  Wt      = (_Float16*)carve(sizeof(_Float16) * 192 * GSTR);

  const int BLK = 256;
  dim3 b(BLK);
  dim3 gridWaveN((N + 3) / 4);
  dim3 gridBin((E + BLK * EPB - 1) / (BLK * EPB));

  // ---- CSR build (bucket-first) ----
  hipMemsetAsync(hist, 0, sizeof(int) * NB, stream);
  k_hist<<<dim3(256), b, 0, stream>>>(ei + E, hist, E, bsh);
  k_prefix<<<dim3(1), dim3(64), 0, stream>>>(hist, bbase, bcur);
  k_bin<<<gridBin, b, 0, stream>>>(ei, pairs, bcur, E, bsh);
  k_csr<<<dim3(nbu), b, 0, stream>>>(pairs, bbase, row_off, deg, csr_src, N, bsh);

  // ---- weight prep ----
  k0_fuse<<<dim3(4), b, 0, stream>>>(projW, projB, g1Wl, g1Wr, Wfl, Wfr, bfl, bfr);
  k_prep<<<dim3(48), b, 0, stream>>>(gruWi, Wt);

  // ---- pipeline ----
  k1_xlxr<<<gridWaveN, b, 0, stream>>>(nf, Wfl, Wfr, bfl, bfr, XL, XR, N);
  k_agg<<<gridWaveN, b, 0, stream>>>(csr_src, row_off, deg, XL, XR, g1att, g1b, ln1g, ln1b, Y, N);
  k3_lr<<<dim3(1280), b, 0, stream>>>(Y, g2Wl, g2Wr, XL, XR, N);
  k_agg<<<gridWaveN, b, 0, stream>>>(csr_src, row_off, deg, XL, XR, g2att, g2b, ln2g, ln2b, Y, N);
  k5_gru_mfma<<<dim3(800), b, 0, stream>>>(Y, Wt, gruBi, gruBh,
                                           huW, hub, hfW, hfb, hoW, hob, hcW, hcb, out, N);
}

// Round 10
// 433.871 us; speedup vs baseline: 3.7756x; 1.0547x over previous
//
#include <hip/hip_runtime.h>

#define NDIM 14
#define HDIM 64
#define NB 512         // scatter buckets
#define EPB 16         // edges per thread in k_bin
#define GSTR 72        // padded col stride (halfs) for LDS-staged f16 weights

typedef __attribute__((ext_vector_type(8))) _Float16 half8;
typedef __attribute__((ext_vector_type(2))) __fp16 fp16x2;   // builtin interop type
typedef __attribute__((ext_vector_type(4))) float f32x4;

static __device__ __forceinline__ float sigmoidf_(float x) { return 1.f / (1.f + __expf(-x)); }
static __device__ __forceinline__ float lrelu_(float x) { return x > 0.f ? x : 0.2f * x; }

static __device__ __forceinline__ float readlane_f(float x, int lane) {
  return __int_as_float(__builtin_amdgcn_readlane(__float_as_int(x), lane));
}

template <int CTRL>
static __device__ __forceinline__ float dpp_add_f(float x) {
  int v = __builtin_amdgcn_update_dpp(0, __float_as_int(x), CTRL, 0xF, 0xF, true);
  return x + __int_as_float(v);
}

// f32 sum over each 16-lane DPP row
static __device__ __forceinline__ float reduce16(float p) {
  p = dpp_add_f<0xB1>(p);
  p = dpp_add_f<0x4E>(p);
  p = dpp_add_f<0x141>(p);
  p = dpp_add_f<0x140>(p);
  return p;
}
// f32 sum within each 32-lane half
static __device__ __forceinline__ float head_reduce32(float p) {
  p = reduce16(p);
  p += __int_as_float(__builtin_amdgcn_ds_swizzle(__float_as_int(p), 0x401F));
  return p;
}
static __device__ __forceinline__ float full_reduce64(float p) {
  p = head_reduce32(p);
  p += __shfl_xor(p, 32, 64);
  return p;
}

// ---- packed f16 helpers ----
static __device__ __forceinline__ unsigned pk_add(unsigned a, unsigned b) {
  unsigned d; asm("v_pk_add_f16 %0, %1, %2" : "=v"(d) : "v"(a), "v"(b)); return d;
}
static __device__ __forceinline__ unsigned pk_mul(unsigned a, unsigned b) {
  unsigned d; asm("v_pk_mul_f16 %0, %1, %2" : "=v"(d) : "v"(a), "v"(b)); return d;
}
static __device__ __forceinline__ unsigned pk_max(unsigned a, unsigned b) {
  unsigned d; asm("v_pk_max_f16 %0, %1, %2" : "=v"(d) : "v"(a), "v"(b)); return d;
}
static __device__ __forceinline__ unsigned cvt_pk_u(float a, float b) {
  fp16x2 h = __builtin_amdgcn_cvt_pkrtz(a, b);
  unsigned u; __builtin_memcpy(&u, &h, 4); return u;
}
static __device__ __forceinline__ fp16x2 as_h2(unsigned u) {
  fp16x2 h; __builtin_memcpy(&h, &u, 4); return h;
}
static __device__ __forceinline__ float cvt_lo(unsigned u) {
  float r; asm("v_cvt_f32_f16 %0, %1" : "=v"(r) : "v"(u)); return r;
}
// packed f16 sum within each 32-lane half (swizzles on DS pipe)
static __device__ __forceinline__ unsigned pk_reduce32(unsigned p) {
  p = pk_add(p, (unsigned)__builtin_amdgcn_ds_swizzle((int)p, 0x041F)); // xor1
  p = pk_add(p, (unsigned)__builtin_amdgcn_ds_swizzle((int)p, 0x081F)); // xor2
  p = pk_add(p, (unsigned)__builtin_amdgcn_ds_swizzle((int)p, 0x101F)); // xor4
  p = pk_add(p, (unsigned)__builtin_amdgcn_ds_swizzle((int)p, 0x201F)); // xor8
  p = pk_add(p, (unsigned)__builtin_amdgcn_ds_swizzle((int)p, 0x401F)); // xor16
  return p;
}

// ======================= CSR build (bucket-first, LDS-local) =======================
__global__ void k_hist(const int* __restrict__ dst, int* __restrict__ hist, int E, int bsh) {
  __shared__ int h[NB];
  for (int i = threadIdx.x; i < NB; i += 256) h[i] = 0;
  __syncthreads();
  for (int e = blockIdx.x * 256 + threadIdx.x; e < E; e += gridDim.x * 256)
    atomicAdd(&h[dst[e] >> bsh], 1);
  __syncthreads();
  for (int i = threadIdx.x; i < NB; i += 256)
    if (h[i]) atomicAdd(&hist[i], h[i]);
}

// parallel prefix over NB=512 buckets: 1 block, 512 threads
__global__ void k_prefix(const int* __restrict__ hist, int* __restrict__ base,
                         int* __restrict__ bcur) {
  __shared__ int wt[8];
  int t = threadIdx.x;
  int lane = t & 63, w = t >> 6;
  int v = hist[t];
  int x = v;
#pragma unroll
  for (int m = 1; m <= 32; m <<= 1) {
    int u = __shfl_up(x, m, 64);
    if (lane >= m) x += u;
  }
  if (lane == 63) wt[w] = x;
  __syncthreads();
  if (t == 0) {
    int a = 0;
#pragma unroll
    for (int i = 0; i < 8; ++i) { int tmp = wt[i]; wt[i] = a; a += tmp; }
  }
  __syncthreads();
  int excl = wt[w] + x - v;
  base[t] = excl;
  bcur[t] = excl;
  if (t == NB - 1) base[NB] = excl + v;
}

__global__ void __launch_bounds__(256) k_bin(const int* __restrict__ ei,
                      long long* __restrict__ pairs, int* __restrict__ bucket_cur,
                      int E, int bsh) {
  __shared__ int h[NB];
  __shared__ int gb[NB];
  int t = threadIdx.x;
  for (int i = t; i < NB; i += 256) h[i] = 0;
  __syncthreads();
  int c0 = blockIdx.x * (256 * EPB);
  long long pr[EPB];
  int br[EPB];
#pragma unroll
  for (int i = 0; i < EPB; ++i) {
    int e = c0 + t + i * 256;
    if (e < E) {
      int s = ei[e], d = ei[E + e];
      int b = d >> bsh;
      int r = atomicAdd(&h[b], 1);
      pr[i] = ((long long)d << 32) | (unsigned)s;
      br[i] = b | (r << 9);
    } else br[i] = -1;
  }
  __syncthreads();
  for (int i = t; i < NB; i += 256)
    if (h[i]) gb[i] = atomicAdd(&bucket_cur[i], h[i]);
  __syncthreads();
#pragma unroll
  for (int i = 0; i < EPB; ++i) {
    if (br[i] >= 0) pairs[gb[br[i] & (NB - 1)] + (br[i] >> 9)] = pr[i];
  }
}

__global__ void __launch_bounds__(256) k_csr(const long long* __restrict__ pairs,
                      const int* __restrict__ base, int* __restrict__ row_off,
                      int* __restrict__ deg, int* __restrict__ csr_src, int N, int bsh) {
  __shared__ int h[1024];
  __shared__ int cu[1024];
  __shared__ int wtot[4];
  int b = blockIdx.x;
  int node0 = b << bsh;
  int range = 1 << bsh;
  int nr = N - node0; if (nr > range) nr = range;
  if (nr <= 0) return;
  int e0 = base[b], e1 = base[b + 1];
  int tid = threadIdx.x;
  for (int i = tid; i < range; i += 256) h[i] = 0;
  __syncthreads();
  for (int e = e0 + tid; e < e1; e += 256)
    atomicAdd(&h[(int)(pairs[e] >> 32) - node0], 1);
  __syncthreads();
  if (range == 256) {
    int lane = tid & 63, wid = tid >> 6;
    int v = (tid < nr) ? h[tid] : 0;
    int x = v;
#pragma unroll
    for (int m = 1; m <= 32; m <<= 1) {
      int t2 = __shfl_up(x, m, 64);
      if (lane >= m) x += t2;
    }
    if (lane == 63) wtot[wid] = x;
    __syncthreads();
    int woff = 0;
#pragma unroll
    for (int w = 0; w < 4; ++w) woff += (w < wid) ? wtot[w] : 0;
    int excl = woff + x - v;
    if (tid < nr) {
      row_off[node0 + tid] = e0 + excl;
      deg[node0 + tid] = v;
      cu[tid] = excl;
    }
  } else {
    if (tid == 0) {
      int acc = 0;
      for (int i = 0; i < nr; ++i) {
        row_off[node0 + i] = e0 + acc;
        deg[node0 + i] = h[i];
        cu[i] = acc;
        acc += h[i];
      }
    }
  }
  __syncthreads();
  for (int e = e0 + tid; e < e1; e += 256) {
    long long pk = pairs[e];
    int d = (int)(pk >> 32), s = (int)pk;
    int p = atomicAdd(&cu[d - node0], 1);
    csr_src[e0 + p] = s;
  }
}

// ======================= weight prep =======================
__global__ void k0_fuse(const float* __restrict__ projW, const float* __restrict__ projB,
                        const float* __restrict__ Wl, const float* __restrict__ Wr,
                        float* __restrict__ Wfl, float* __restrict__ Wfr,
                        float* __restrict__ bfl, float* __restrict__ bfr) {
  int t = blockIdx.x * blockDim.x + threadIdx.x;
  int total = (NDIM + 1) * HDIM;
  if (t >= total) return;
  int r = t / HDIM, c = t % HDIM;
  float al = 0.f, ar = 0.f;
  if (r < NDIM) {
    for (int k = 0; k < HDIM; ++k) {
      float w = projW[r * HDIM + k];
      al += w * Wl[k * HDIM + c];
      ar += w * Wr[k * HDIM + c];
    }
    Wfl[r * HDIM + c] = al;
    Wfr[r * HDIM + c] = ar;
  } else {
    for (int k = 0; k < HDIM; ++k) {
      float w = projB[k];
      al += w * Wl[k * HDIM + c];
      ar += w * Wr[k * HDIM + c];
    }
    bfl[c] = al;
    bfr[c] = ar;
  }
}

// GRU Wi f32 -> f16 col-major padded
__global__ void k_prep(const float* __restrict__ Wi, _Float16* __restrict__ Wt) {
  int t = blockIdx.x * blockDim.x + threadIdx.x;
  if (t >= 192 * 64) return;
  int col = t / 64, row = t % 64;
  Wt[col * GSTR + row] = (_Float16)Wi[row * 192 + col];
}

// [Wl|Wr] f32 -> f16 col-major padded (128 cols)
__global__ void k_prep_lr(const float* __restrict__ Wl, const float* __restrict__ Wr,
                          _Float16* __restrict__ Wb) {
  int t = blockIdx.x * blockDim.x + threadIdx.x;
  if (t >= 128 * 64) return;
  int col = t >> 6, row = t & 63;
  float v = (col < 64) ? Wl[row * 64 + col] : Wr[row * 64 + (col - 64)];
  Wb[col * GSTR + row] = (_Float16)v;
}

// ======================= k1: XL1(f16)/XR1(f32) from node features =======================
__global__ void k1_xlxr(const float* __restrict__ nf, const float* __restrict__ Wfl,
                        const float* __restrict__ Wfr, const float* __restrict__ bfl,
                        const float* __restrict__ bfr, _Float16* __restrict__ XL16,
                        float* __restrict__ XR, int N) {
  int n = blockIdx.x * (blockDim.x >> 6) + (threadIdx.x >> 6);
  int j = threadIdx.x & 63;
  if (n >= N) return;
  float nfv = (j < NDIM) ? nf[n * NDIM + j] : 0.f;
  float al = bfl[j], ar = bfr[j];
#pragma unroll
  for (int k = 0; k < NDIM; ++k) {
    float xk = readlane_f(nfv, k);
    al += xk * Wfl[k * HDIM + j];
    ar += xk * Wfr[k * HDIM + j];
  }
  XL16[n * HDIM + j] = (_Float16)al;
  XR[n * HDIM + j] = ar;
}

// ======================= k_agg: packed-f16 pull-aggregate + softmax + ELU + LN =======================
__global__ void k_agg(const int* __restrict__ csr_src, const int* __restrict__ row_off,
                      const int* __restrict__ deg, const _Float16* __restrict__ XL16,
                      const float* __restrict__ XR, const float* __restrict__ att,
                      const float* __restrict__ gb, const float* __restrict__ lng,
                      const float* __restrict__ lnb, float* __restrict__ Y, int N) {
  int n = blockIdx.x * (blockDim.x >> 6) + (threadIdx.x >> 6);
  int j = threadIdx.x & 63;
  if (n >= N) return;
  float xr = XR[n * HDIM + j];
  float attv = att[j];
  // packed per-lane constants
  unsigned xr_pk  = cvt_pk_u(xr, xr);
  unsigned att_pk = cvt_pk_u(attv, attv);
  unsigned c02_pk = 0x32663266u;                    // (0.2, 0.2) f16
  fp16x2 one_pk = as_h2(0x3C003C00u);               // (1.0, 1.0) f16
  const char* xlb = (const char*)XL16;
  int voff = j << 1;

  // self-loop (f32 path)
  float xl = (float)XL16[(size_t)n * HDIM + j];
  float p = head_reduce32(lrelu_(xl + xr) * attv);
  float ex = __expf(p);
  float acc = ex * xl;
  float den = ex;

  int base = row_off[n], cnt = deg[n];
  for (int c0 = 0; c0 < cnt; c0 += 64) {
    int m_ = cnt - c0; if (m_ > 64) m_ = 64;
    int sidx = (j < m_) ? csr_src[base + c0 + j] : 0;
    int npairs = m_ >> 1;
    for (int pp = 0; pp < npairs; pp += 4) {
      int c = npairs - pp; if (c > 4) c = 4;
      unsigned x[4];
#pragma unroll
      for (int u = 0; u < 4; ++u) {
        if (u < c) {
          int sa = __builtin_amdgcn_readlane(sidx, 2 * (pp + u));
          int sb = __builtin_amdgcn_readlane(sidx, 2 * (pp + u) + 1);
          unsigned short ua = *(const unsigned short*)(xlb + (((long)sa) << 7) + voff);
          unsigned short ub = *(const unsigned short*)(xlb + (((long)sb) << 7) + voff);
          x[u] = (unsigned)ua | ((unsigned)ub << 16);
        }
      }
#pragma unroll
      for (int u = 0; u < 4; ++u) {
        if (u < c) {
          unsigned t = pk_add(x[u], xr_pk);           // xl + xr
          unsigned lr = pk_max(t, pk_mul(t, c02_pk)); // leaky relu
          unsigned sc = pk_mul(lr, att_pk);           // * att
          sc = pk_reduce32(sc);                       // per-head sums (packed pair)
          float s_a = cvt_lo(sc), s_b = cvt_lo(sc >> 16);
          float e_a = __expf(s_a), e_b = __expf(s_b);
          fp16x2 exk = __builtin_amdgcn_cvt_pkrtz(e_a, e_b);
          acc = __builtin_amdgcn_fdot2(as_h2(x[u]), exk, acc, false);
          den = __builtin_amdgcn_fdot2(exk, one_pk, den, false);
        }
      }
    }
    if (m_ & 1) {   // odd tail, f32 path
      int s = __builtin_amdgcn_readlane(sidx, m_ - 1);
      float xls = (float)XL16[(size_t)s * HDIM + j];
      float pq = head_reduce32(lrelu_(xls + xr) * attv);
      float ee = __expf(pq);
      acc += ee * xls;
      den += ee;
    }
  }

  float y = acc / (den + 1e-16f) + gb[j];
  y = y > 0.f ? y : __expf(y) - 1.f;
  float mu = full_reduce64(y) * (1.f / 64.f);
  float d = y - mu;
  float var = full_reduce64(d * d) * (1.f / 64.f);
  Y[n * HDIM + j] = d * rsqrtf(var + 1e-5f) * lng[j] + lnb[j];
}

// ======================= k3: Y -> XL2(f16)/XR2(f32) via f16 MFMA =======================
__global__ void __launch_bounds__(256) k3_mfma(const float* __restrict__ Y,
                      const _Float16* __restrict__ Wb, _Float16* __restrict__ XL16,
                      float* __restrict__ XR, int N) {
  __shared__ _Float16 W[128 * GSTR];
  for (int i = threadIdx.x; i < 128 * GSTR / 8; i += 256)
    ((int4*)W)[i] = ((const int4*)Wb)[i];
  __syncthreads();
  int wave = blockIdx.x * 4 + (threadIdx.x >> 6);
  int nwaves = gridDim.x * 4;
  int lane = threadIdx.x & 63;
  int c = lane & 15, q = lane >> 4;
  for (int n0 = wave * 16; n0 < N; n0 += nwaves * 16) {
    bool okrow = (n0 + c) < N;
    const float* yrow = Y + (size_t)(n0 + c) * HDIM + q * 8;
    float4 v0 = {0,0,0,0}, v1 = {0,0,0,0}, v2 = {0,0,0,0}, v3 = {0,0,0,0};
    if (okrow) {
      v0 = *(const float4*)(yrow);
      v1 = *(const float4*)(yrow + 4);
      v2 = *(const float4*)(yrow + 32);
      v3 = *(const float4*)(yrow + 36);
    }
    half8 a0, a1;
    a0[0]=(_Float16)v0.x; a0[1]=(_Float16)v0.y; a0[2]=(_Float16)v0.z; a0[3]=(_Float16)v0.w;
    a0[4]=(_Float16)v1.x; a0[5]=(_Float16)v1.y; a0[6]=(_Float16)v1.z; a0[7]=(_Float16)v1.w;
    a1[0]=(_Float16)v2.x; a1[1]=(_Float16)v2.y; a1[2]=(_Float16)v2.z; a1[3]=(_Float16)v2.w;
    a1[4]=(_Float16)v3.x; a1[5]=(_Float16)v3.y; a1[6]=(_Float16)v3.z; a1[7]=(_Float16)v3.w;

    f32x4 acc[8];
#pragma unroll
    for (int t = 0; t < 8; ++t) acc[t] = (f32x4){0.f, 0.f, 0.f, 0.f};
#pragma unroll
    for (int t = 0; t < 8; ++t) {
      half8 b0 = *(const half8*)(&W[(t * 16 + c) * GSTR + q * 8]);
      half8 b1 = *(const half8*)(&W[(t * 16 + c) * GSTR + 32 + q * 8]);
      acc[t] = __builtin_amdgcn_mfma_f32_16x16x32_f16(a0, b0, acc[t], 0, 0, 0);
      acc[t] = __builtin_amdgcn_mfma_f32_16x16x32_f16(a1, b1, acc[t], 0, 0, 0);
    }
#pragma unroll
    for (int t = 0; t < 4; ++t) {
#pragma unroll
      for (int i = 0; i < 4; ++i) {
        int n = n0 + q * 4 + i;
        if (n < N) {
          XL16[(size_t)n * HDIM + t * 16 + c] = (_Float16)acc[t][i];
          XR[(size_t)n * HDIM + t * 16 + c] = acc[t + 4][i];
        }
      }
    }
  }
}

// ======================= k5: GRU via f16 MFMA + heads =======================
__global__ void __launch_bounds__(256) k5_gru_mfma(const float* __restrict__ Y,
                       const _Float16* __restrict__ Wt,
                       const float* __restrict__ bi, const float* __restrict__ bh,
                       const float* __restrict__ huW, const float* __restrict__ hub,
                       const float* __restrict__ hfW, const float* __restrict__ hfb,
                       const float* __restrict__ hoW, const float* __restrict__ hob,
                       const float* __restrict__ hcW, const float* __restrict__ hcb,
                       float* __restrict__ out, int N) {
  __shared__ _Float16 W[192 * GSTR];
  __shared__ float BS[192];
  __shared__ float BHN[64];
  for (int i = threadIdx.x; i < 192 * GSTR / 8; i += 256)
    ((int4*)W)[i] = ((const int4*)Wt)[i];
  for (int i = threadIdx.x; i < 192; i += 256) BS[i] = bi[i] + (i < 128 ? bh[i] : 0.f);
  for (int i = threadIdx.x; i < 64; i += 256) BHN[i] = bh[128 + i];
  __syncthreads();

  int wave = blockIdx.x * 4 + (threadIdx.x >> 6);
  int nwaves = gridDim.x * 4;
  int lane = threadIdx.x & 63;
  int c = lane & 15, q = lane >> 4;

  float hu_[4], hf_[4], ho_[4], hc_[4];
#pragma unroll
  for (int t = 0; t < 4; ++t) {
    hu_[t] = huW[t * 16 + c];
    hf_[t] = hfW[t * 16 + c];
    ho_[t] = hoW[t * 16 + c];
    hc_[t] = hcW[t * 16 + c];
  }
  float hub0 = hub[0], hfb0 = hfb[0], hob0 = hob[0], hcb0 = hcb[0];

  for (int n0 = wave * 16; n0 < N; n0 += nwaves * 16) {
    bool okrow = (n0 + c) < N;
    const float* yrow = Y + (size_t)(n0 + c) * HDIM + q * 8;
    float4 v0 = {0,0,0,0}, v1 = {0,0,0,0}, v2 = {0,0,0,0}, v3 = {0,0,0,0};
    if (okrow) {
      v0 = *(const float4*)(yrow);
      v1 = *(const float4*)(yrow + 4);
      v2 = *(const float4*)(yrow + 32);
      v3 = *(const float4*)(yrow + 36);
    }
    half8 a0, a1;
    a0[0]=(_Float16)v0.x; a0[1]=(_Float16)v0.y; a0[2]=(_Float16)v0.z; a0[3]=(_Float16)v0.w;
    a0[4]=(_Float16)v1.x; a0[5]=(_Float16)v1.y; a0[6]=(_Float16)v1.z; a0[7]=(_Float16)v1.w;
    a1[0]=(_Float16)v2.x; a1[1]=(_Float16)v2.y; a1[2]=(_Float16)v2.z; a1[3]=(_Float16)v2.w;
    a1[4]=(_Float16)v3.x; a1[5]=(_Float16)v3.y; a1[6]=(_Float16)v3.z; a1[7]=(_Float16)v3.w;

    f32x4 acc[12];
#pragma unroll
    for (int t = 0; t < 12; ++t) acc[t] = (f32x4){0.f, 0.f, 0.f, 0.f};
#pragma unroll
    for (int t = 0; t < 12; ++t) {
      half8 b0 = *(const half8*)(&W[(t * 16 + c) * GSTR + q * 8]);
      half8 b1 = *(const half8*)(&W[(t * 16 + c) * GSTR + 32 + q * 8]);
      acc[t] = __builtin_amdgcn_mfma_f32_16x16x32_f16(a0, b0, acc[t], 0, 0, 0);
      acc[t] = __builtin_amdgcn_mfma_f32_16x16x32_f16(a1, b1, acc[t], 0, 0, 0);
    }

    float hv[4][4];
#pragma unroll
    for (int t = 0; t < 4; ++t) {
      int cr = t * 16 + c;
      float bsr = BS[cr], bsz = BS[64 + cr], bsn = BS[128 + cr], bhn = BHN[cr];
#pragma unroll
      for (int i = 0; i < 4; ++i) {
        float r = sigmoidf_(acc[t][i] + bsr);
        float z = sigmoidf_(acc[t + 4][i] + bsz);
        float nn = tanhf(acc[t + 8][i] + bsn + r * bhn);
        hv[t][i] = (1.f - z) * nn;
      }
    }
#pragma unroll
    for (int i = 0; i < 4; ++i) {
      float pu = 0.f, pf = 0.f, po = 0.f, pc = 0.f;
#pragma unroll
      for (int t = 0; t < 4; ++t) {
        pu += hv[t][i] * hu_[t];
        pf += hv[t][i] * hf_[t];
        po += hv[t][i] * ho_[t];
        pc += hv[t][i] * hc_[t];
      }
      pu = reduce16(pu); pf = reduce16(pf); po = reduce16(po); pc = reduce16(pc);
      int n = n0 + q * 4 + i;
      if (n < N) {
        if (c == 0) out[n]         = sigmoidf_(pu + hub0);
        if (c == 1) out[N + n]     = sigmoidf_(pf + hfb0);
        if (c == 2) out[2 * N + n] = fmaxf(po + hob0, 0.f);
        if (c == 3) out[3 * N + n] = sigmoidf_(pc + hcb0);
      }
    }
  }
}

// ======================= launch =======================
extern "C" void kernel_launch(void* const* d_in, const int* in_sizes, int n_in,
                              void* d_out, int out_size, void* d_ws, size_t ws_size,
                              hipStream_t stream) {
  const float* nf    = (const float*)d_in[0];
  const int*   ei    = (const int*)d_in[1];
  const float* projW = (const float*)d_in[2];
  const float* projB = (const float*)d_in[3];
  const float* g1Wl  = (const float*)d_in[4];
  const float* g1Wr  = (const float*)d_in[5];
  const float* g1att = (const float*)d_in[6];
  const float* g1b   = (const float*)d_in[7];
  const float* g2Wl  = (const float*)d_in[8];
  const float* g2Wr  = (const float*)d_in[9];
  const float* g2att = (const float*)d_in[10];
  const float* g2b   = (const float*)d_in[11];
  const float* ln1g  = (const float*)d_in[12];
  const float* ln1b  = (const float*)d_in[13];
  const float* ln2g  = (const float*)d_in[14];
  const float* ln2b  = (const float*)d_in[15];
  const float* gruWi = (const float*)d_in[16];
  // d_in[17] = gru_Wh, unused (h0 = 0)
  const float* gruBi = (const float*)d_in[18];
  const float* gruBh = (const float*)d_in[19];
  const float* huW = (const float*)d_in[20];
  const float* hub = (const float*)d_in[21];
  const float* hfW = (const float*)d_in[22];
  const float* hfb = (const float*)d_in[23];
  const float* hoW = (const float*)d_in[24];
  const float* hob = (const float*)d_in[25];
  const float* hcW = (const float*)d_in[26];
  const float* hcb = (const float*)d_in[27];
  float* out = (float*)d_out;

  const int N = in_sizes[0] / NDIM;
  const int E = in_sizes[1] / 2;
  int bsh = 8;
  while (((N - 1) >> bsh) >= NB) ++bsh;
  const int nbu = (N + (1 << bsh) - 1) >> bsh;

  char* ws = (char*)d_ws;
  size_t off = 0;
  auto carve = [&](size_t bytes) { void* p = ws + off; off += (bytes + 255) & ~size_t(255); return p; };
  _Float16*  XL16    = (_Float16*)carve(sizeof(_Float16) * N * HDIM);
  float*     XR      = (float*)carve(sizeof(float) * N * HDIM);
  float*     Y       = (float*)carve(sizeof(float) * N * HDIM);
  long long* pairs   = (long long*)carve(sizeof(long long) * E);
  int*       csr_src = (int*)carve(sizeof(int) * E);
  int*       deg     = (int*)carve(sizeof(int) * N);
  int*       row_off = (int*)carve(sizeof(int) * N);
  int*       hist    = (int*)carve(sizeof(int) * NB);
  int*       bbase   = (int*)carve(sizeof(int) * (NB + 1));
  int*       bcur    = (int*)carve(sizeof(int) * NB);
  float*     Wfl     = (float*)carve(sizeof(float) * NDIM * HDIM);
  float*     Wfr     = (float*)carve(sizeof(float) * NDIM * HDIM);
  float*     bfl     = (float*)carve(sizeof(float) * HDIM);
  float*     bfr     = (float*)carve(sizeof(float) * HDIM);
  _Float16*  Wt      = (_Float16*)carve(sizeof(_Float16) * 192 * GSTR);
  _Float16*  Wb      = (_Float16*)carve(sizeof(_Float16) * 128 * GSTR);

  const int BLK = 256;
  dim3 b(BLK);
  dim3 gridWaveN((N + 3) / 4);
  dim3 gridBin((E + BLK * EPB - 1) / (BLK * EPB));

  // ---- CSR build ----
  (void)hipMemsetAsync(hist, 0, sizeof(int) * NB, stream);
  k_hist<<<dim3(256), b, 0, stream>>>(ei + E, hist, E, bsh);
  k_prefix<<<dim3(1), dim3(NB), 0, stream>>>(hist, bbase, bcur);
  k_bin<<<gridBin, b, 0, stream>>>(ei, pairs, bcur, E, bsh);
  k_csr<<<dim3(nbu), b, 0, stream>>>(pairs, bbase, row_off, deg, csr_src, N, bsh);

  // ---- weight prep ----
  k0_fuse<<<dim3(4), b, 0, stream>>>(projW, projB, g1Wl, g1Wr, Wfl, Wfr, bfl, bfr);
  k_prep<<<dim3(48), b, 0, stream>>>(gruWi, Wt);
  k_prep_lr<<<dim3(32), b, 0, stream>>>(g2Wl, g2Wr, Wb);

  // ---- pipeline ----
  k1_xlxr<<<gridWaveN, b, 0, stream>>>(nf, Wfl, Wfr, bfl, bfr, XL16, XR, N);
  k_agg<<<gridWaveN, b, 0, stream>>>(csr_src, row_off, deg, XL16, XR, g1att, g1b, ln1g, ln1b, Y, N);
  k3_mfma<<<dim3(800), b, 0, stream>>>(Y, Wb, XL16, XR, N);
  k_agg<<<gridWaveN, b, 0, stream>>>(csr_src, row_off, deg, XL16, XR, g2att, g2b, ln2g, ln2b, Y, N);
  k5_gru_mfma<<<dim3(800), b, 0, stream>>>(Y, Wt, gruBi, gruBh,
                                           huW, hub, hfW, hfb, hoW, hob, hcW, hcb, out, N);
}

// Round 11
// 410.653 us; speedup vs baseline: 3.9891x; 1.0565x over previous
//
#include <hip/hip_runtime.h>

#define NDIM 14
#define HDIM 64
#define NB 512         // scatter buckets
#define EPB 16         // edges per thread in k_bin
#define GSTR 72        // padded col stride (halfs) for LDS-staged f16 weights

typedef __attribute__((ext_vector_type(8))) _Float16 half8;
typedef __attribute__((ext_vector_type(2))) __fp16 fp16x2;   // builtin interop type
typedef __attribute__((ext_vector_type(4))) float f32x4;

static __device__ __forceinline__ float sigmoidf_(float x) { return 1.f / (1.f + __expf(-x)); }
static __device__ __forceinline__ float lrelu_(float x) { return x > 0.f ? x : 0.2f * x; }

static __device__ __forceinline__ float readlane_f(float x, int lane) {
  return __int_as_float(__builtin_amdgcn_readlane(__float_as_int(x), lane));
}

template <int CTRL>
static __device__ __forceinline__ float dpp_add_f(float x) {
  int v = __builtin_amdgcn_update_dpp(0, __float_as_int(x), CTRL, 0xF, 0xF, true);
  return x + __int_as_float(v);
}

// f32 sum over each 16-lane DPP row
static __device__ __forceinline__ float reduce16(float p) {
  p = dpp_add_f<0xB1>(p);
  p = dpp_add_f<0x4E>(p);
  p = dpp_add_f<0x141>(p);
  p = dpp_add_f<0x140>(p);
  return p;
}
// f32 sum within each 32-lane half
static __device__ __forceinline__ float head_reduce32(float p) {
  p = reduce16(p);
  p += __int_as_float(__builtin_amdgcn_ds_swizzle(__float_as_int(p), 0x401F));
  return p;
}
static __device__ __forceinline__ float full_reduce64(float p) {
  p = head_reduce32(p);
  p += __shfl_xor(p, 32, 64);
  return p;
}

// ---- packed f16 helpers ----
static __device__ __forceinline__ unsigned pk_add(unsigned a, unsigned b) {
  unsigned d; asm("v_pk_add_f16 %0, %1, %2" : "=v"(d) : "v"(a), "v"(b)); return d;
}
static __device__ __forceinline__ unsigned pk_mul(unsigned a, unsigned b) {
  unsigned d; asm("v_pk_mul_f16 %0, %1, %2" : "=v"(d) : "v"(a), "v"(b)); return d;
}
static __device__ __forceinline__ unsigned pk_max(unsigned a, unsigned b) {
  unsigned d; asm("v_pk_max_f16 %0, %1, %2" : "=v"(d) : "v"(a), "v"(b)); return d;
}
static __device__ __forceinline__ unsigned cvt_pk_u(float a, float b) {
  fp16x2 h = __builtin_amdgcn_cvt_pkrtz(a, b);
  unsigned u; __builtin_memcpy(&u, &h, 4); return u;
}
static __device__ __forceinline__ fp16x2 as_h2(unsigned u) {
  fp16x2 h; __builtin_memcpy(&h, &u, 4); return h;
}
static __device__ __forceinline__ float cvt_lo(unsigned u) {
  float r; asm("v_cvt_f32_f16 %0, %1" : "=v"(r) : "v"(u)); return r;
}
// packed add of DPP-permuted self (packed halves travel together; lane pairings
// identical to the verified f32 reduce16 path)
template <int CTRL>
static __device__ __forceinline__ unsigned pk_dpp_add(unsigned x) {
  unsigned v = (unsigned)__builtin_amdgcn_update_dpp(0, (int)x, CTRL, 0xF, 0xF, true);
  return pk_add(x, v);
}
// packed f16 sum within each 32-lane half: 4 DPP + 1 swizzle (short critical path)
static __device__ __forceinline__ unsigned pk_reduce32(unsigned p) {
  p = pk_dpp_add<0xB1>(p);     // xor1
  p = pk_dpp_add<0x4E>(p);     // xor2
  p = pk_dpp_add<0x141>(p);    // 8-group mirror
  p = pk_dpp_add<0x140>(p);    // 16-group mirror
  p = pk_add(p, (unsigned)__builtin_amdgcn_ds_swizzle((int)p, 0x401F)); // xor16
  return p;
}

// ======================= CSR build (bucket-first, LDS-local) =======================
__global__ void k_hist(const int* __restrict__ dst, int* __restrict__ hist, int E, int bsh) {
  __shared__ int h[NB];
  for (int i = threadIdx.x; i < NB; i += 256) h[i] = 0;
  __syncthreads();
  for (int e = blockIdx.x * 256 + threadIdx.x; e < E; e += gridDim.x * 256)
    atomicAdd(&h[dst[e] >> bsh], 1);
  __syncthreads();
  for (int i = threadIdx.x; i < NB; i += 256)
    if (h[i]) atomicAdd(&hist[i], h[i]);
}

// parallel prefix over NB=512 buckets: 1 block, 512 threads
__global__ void k_prefix(const int* __restrict__ hist, int* __restrict__ base,
                         int* __restrict__ bcur) {
  __shared__ int wt[8];
  int t = threadIdx.x;
  int lane = t & 63, w = t >> 6;
  int v = hist[t];
  int x = v;
#pragma unroll
  for (int m = 1; m <= 32; m <<= 1) {
    int u = __shfl_up(x, m, 64);
    if (lane >= m) x += u;
  }
  if (lane == 63) wt[w] = x;
  __syncthreads();
  if (t == 0) {
    int a = 0;
#pragma unroll
    for (int i = 0; i < 8; ++i) { int tmp = wt[i]; wt[i] = a; a += tmp; }
  }
  __syncthreads();
  int excl = wt[w] + x - v;
  base[t] = excl;
  bcur[t] = excl;
  if (t == NB - 1) base[NB] = excl + v;
}

__global__ void __launch_bounds__(256) k_bin(const int* __restrict__ ei,
                      long long* __restrict__ pairs, int* __restrict__ bucket_cur,
                      int E, int bsh) {
  __shared__ int h[NB];
  __shared__ int gb[NB];
  int t = threadIdx.x;
  for (int i = t; i < NB; i += 256) h[i] = 0;
  __syncthreads();
  int c0 = blockIdx.x * (256 * EPB);
  long long pr[EPB];
  int br[EPB];
#pragma unroll
  for (int i = 0; i < EPB; ++i) {
    int e = c0 + t + i * 256;
    if (e < E) {
      int s = ei[e], d = ei[E + e];
      int b = d >> bsh;
      int r = atomicAdd(&h[b], 1);
      pr[i] = ((long long)d << 32) | (unsigned)s;
      br[i] = b | (r << 9);
    } else br[i] = -1;
  }
  __syncthreads();
  for (int i = t; i < NB; i += 256)
    if (h[i]) gb[i] = atomicAdd(&bucket_cur[i], h[i]);
  __syncthreads();
#pragma unroll
  for (int i = 0; i < EPB; ++i) {
    if (br[i] >= 0) pairs[gb[br[i] & (NB - 1)] + (br[i] >> 9)] = pr[i];
  }
}

__global__ void __launch_bounds__(256) k_csr(const long long* __restrict__ pairs,
                      const int* __restrict__ base, int* __restrict__ row_off,
                      int* __restrict__ deg, int* __restrict__ csr_src, int N, int bsh) {
  __shared__ int h[1024];
  __shared__ int cu[1024];
  __shared__ int wtot[4];
  int b = blockIdx.x;
  int node0 = b << bsh;
  int range = 1 << bsh;
  int nr = N - node0; if (nr > range) nr = range;
  if (nr <= 0) return;
  int e0 = base[b], e1 = base[b + 1];
  int tid = threadIdx.x;
  for (int i = tid; i < range; i += 256) h[i] = 0;
  __syncthreads();
  for (int e = e0 + tid; e < e1; e += 256)
    atomicAdd(&h[(int)(pairs[e] >> 32) - node0], 1);
  __syncthreads();
  if (range == 256) {
    int lane = tid & 63, wid = tid >> 6;
    int v = (tid < nr) ? h[tid] : 0;
    int x = v;
#pragma unroll
    for (int m = 1; m <= 32; m <<= 1) {
      int t2 = __shfl_up(x, m, 64);
      if (lane >= m) x += t2;
    }
    if (lane == 63) wtot[wid] = x;
    __syncthreads();
    int woff = 0;
#pragma unroll
    for (int w = 0; w < 4; ++w) woff += (w < wid) ? wtot[w] : 0;
    int excl = woff + x - v;
    if (tid < nr) {
      row_off[node0 + tid] = e0 + excl;
      deg[node0 + tid] = v;
      cu[tid] = excl;
    }
  } else {
    if (tid == 0) {
      int acc = 0;
      for (int i = 0; i < nr; ++i) {
        row_off[node0 + i] = e0 + acc;
        deg[node0 + i] = h[i];
        cu[i] = acc;
        acc += h[i];
      }
    }
  }
  __syncthreads();
  for (int e = e0 + tid; e < e1; e += 256) {
    long long pk = pairs[e];
    int d = (int)(pk >> 32), s = (int)pk;
    int p = atomicAdd(&cu[d - node0], 1);
    csr_src[e0 + p] = s;
  }
}

// ======================= merged weight prep =======================
// block 0-3: fold proj into layer-1 weights; block 4-51: GRU Wi->f16; block 52-83: [Wl|Wr]->f16
__global__ void k_wprep(const float* __restrict__ projW, const float* __restrict__ projB,
                        const float* __restrict__ Wl1, const float* __restrict__ Wr1,
                        const float* __restrict__ Wi, const float* __restrict__ Wl2,
                        const float* __restrict__ Wr2,
                        float* __restrict__ Wfl, float* __restrict__ Wfr,
                        float* __restrict__ bfl, float* __restrict__ bfr,
                        _Float16* __restrict__ Wt, _Float16* __restrict__ Wb) {
  int blk = blockIdx.x;
  if (blk < 4) {
    int t = blk * 256 + threadIdx.x;
    int total = (NDIM + 1) * HDIM;
    if (t >= total) return;
    int r = t / HDIM, c = t % HDIM;
    float al = 0.f, ar = 0.f;
    if (r < NDIM) {
      for (int k = 0; k < HDIM; ++k) {
        float w = projW[r * HDIM + k];
        al += w * Wl1[k * HDIM + c];
        ar += w * Wr1[k * HDIM + c];
      }
      Wfl[r * HDIM + c] = al;
      Wfr[r * HDIM + c] = ar;
    } else {
      for (int k = 0; k < HDIM; ++k) {
        float w = projB[k];
        al += w * Wl1[k * HDIM + c];
        ar += w * Wr1[k * HDIM + c];
      }
      bfl[c] = al;
      bfr[c] = ar;
    }
  } else if (blk < 52) {
    int t = (blk - 4) * 256 + threadIdx.x;
    if (t >= 192 * 64) return;
    int col = t / 64, row = t % 64;
    Wt[col * GSTR + row] = (_Float16)Wi[row * 192 + col];
  } else {
    int t = (blk - 52) * 256 + threadIdx.x;
    if (t >= 128 * 64) return;
    int col = t >> 6, row = t & 63;
    float v = (col < 64) ? Wl2[row * 64 + col] : Wr2[row * 64 + (col - 64)];
    Wb[col * GSTR + row] = (_Float16)v;
  }
}

// ======================= k1: XL1(f16)/XR1(f32) from node features =======================
__global__ void k1_xlxr(const float* __restrict__ nf, const float* __restrict__ Wfl,
                        const float* __restrict__ Wfr, const float* __restrict__ bfl,
                        const float* __restrict__ bfr, _Float16* __restrict__ XL16,
                        float* __restrict__ XR, int N) {
  int n = blockIdx.x * (blockDim.x >> 6) + (threadIdx.x >> 6);
  int j = threadIdx.x & 63;
  if (n >= N) return;
  float nfv = (j < NDIM) ? nf[n * NDIM + j] : 0.f;
  float al = bfl[j], ar = bfr[j];
#pragma unroll
  for (int k = 0; k < NDIM; ++k) {
    float xk = readlane_f(nfv, k);
    al += xk * Wfl[k * HDIM + j];
    ar += xk * Wfr[k * HDIM + j];
  }
  XL16[n * HDIM + j] = (_Float16)al;
  XR[n * HDIM + j] = ar;
}

// ======================= k_agg: packed-f16 pull-aggregate + softmax + ELU + LN =======================
__global__ void k_agg(const int* __restrict__ csr_src, const int* __restrict__ row_off,
                      const int* __restrict__ deg, const _Float16* __restrict__ XL16,
                      const float* __restrict__ XR, const float* __restrict__ att,
                      const float* __restrict__ gb, const float* __restrict__ lng,
                      const float* __restrict__ lnb, float* __restrict__ Y, int N) {
  int n = blockIdx.x * (blockDim.x >> 6) + (threadIdx.x >> 6);
  int j = threadIdx.x & 63;
  if (n >= N) return;
  float xr = XR[n * HDIM + j];
  float attv = att[j];
  unsigned xr_pk  = cvt_pk_u(xr, xr);
  unsigned att_pk = cvt_pk_u(attv, attv);
  unsigned c02_pk = 0x32663266u;                    // (0.2, 0.2) f16
  fp16x2 one_pk = as_h2(0x3C003C00u);               // (1.0, 1.0) f16
  const char* xlb = (const char*)XL16;
  int voff = j << 1;

  // self-loop (f32 path)
  float xl = (float)XL16[(size_t)n * HDIM + j];
  float p = head_reduce32(lrelu_(xl + xr) * attv);
  float ex = __expf(p);
  float acc = ex * xl;
  float den = ex;

  int base = row_off[n], cnt = deg[n];
  for (int c0 = 0; c0 < cnt; c0 += 64) {
    int m_ = cnt - c0; if (m_ > 64) m_ = 64;
    int sidx = (j < m_) ? csr_src[base + c0 + j] : 0;
    int npairs = m_ >> 1;
    for (int pp = 0; pp < npairs; pp += 8) {
      int c = npairs - pp; if (c > 8) c = 8;
      unsigned x[8];
#pragma unroll
      for (int u = 0; u < 8; ++u) {
        if (u < c) {
          int sa = __builtin_amdgcn_readlane(sidx, 2 * (pp + u));
          int sb = __builtin_amdgcn_readlane(sidx, 2 * (pp + u) + 1);
          unsigned short ua = *(const unsigned short*)(xlb + (((long)sa) << 7) + voff);
          unsigned short ub = *(const unsigned short*)(xlb + (((long)sb) << 7) + voff);
          x[u] = (unsigned)ua | ((unsigned)ub << 16);
        }
      }
#pragma unroll
      for (int u = 0; u < 8; ++u) {
        if (u < c) {
          unsigned t = pk_add(x[u], xr_pk);           // xl + xr
          unsigned lr = pk_max(t, pk_mul(t, c02_pk)); // leaky relu
          unsigned sc = pk_mul(lr, att_pk);           // * att
          sc = pk_reduce32(sc);                       // per-head sums (packed pair)
          float s_a = cvt_lo(sc), s_b = cvt_lo(sc >> 16);
          float e_a = __expf(s_a), e_b = __expf(s_b);
          fp16x2 exk = __builtin_amdgcn_cvt_pkrtz(e_a, e_b);
          acc = __builtin_amdgcn_fdot2(as_h2(x[u]), exk, acc, false);
          den = __builtin_amdgcn_fdot2(exk, one_pk, den, false);
        }
      }
    }
    if (m_ & 1) {   // odd tail, f32 path
      int s = __builtin_amdgcn_readlane(sidx, m_ - 1);
      float xls = (float)XL16[(size_t)s * HDIM + j];
      float pq = head_reduce32(lrelu_(xls + xr) * attv);
      float ee = __expf(pq);
      acc += ee * xls;
      den += ee;
    }
  }

  float y = acc / (den + 1e-16f) + gb[j];
  y = y > 0.f ? y : __expf(y) - 1.f;
  float mu = full_reduce64(y) * (1.f / 64.f);
  float d = y - mu;
  float var = full_reduce64(d * d) * (1.f / 64.f);
  Y[n * HDIM + j] = d * rsqrtf(var + 1e-5f) * lng[j] + lnb[j];
}

// ======================= k3: Y -> XL2(f16)/XR2(f32) via f16 MFMA =======================
__global__ void __launch_bounds__(256) k3_mfma(const float* __restrict__ Y,
                      const _Float16* __restrict__ Wb, _Float16* __restrict__ XL16,
                      float* __restrict__ XR, int N) {
  __shared__ _Float16 W[128 * GSTR];
  for (int i = threadIdx.x; i < 128 * GSTR / 8; i += 256)
    ((int4*)W)[i] = ((const int4*)Wb)[i];
  __syncthreads();
  int wave = blockIdx.x * 4 + (threadIdx.x >> 6);
  int nwaves = gridDim.x * 4;
  int lane = threadIdx.x & 63;
  int c = lane & 15, q = lane >> 4;
  for (int n0 = wave * 16; n0 < N; n0 += nwaves * 16) {
    bool okrow = (n0 + c) < N;
    const float* yrow = Y + (size_t)(n0 + c) * HDIM + q * 8;
    float4 v0 = {0,0,0,0}, v1 = {0,0,0,0}, v2 = {0,0,0,0}, v3 = {0,0,0,0};
    if (okrow) {
      v0 = *(const float4*)(yrow);
      v1 = *(const float4*)(yrow + 4);
      v2 = *(const float4*)(yrow + 32);
      v3 = *(const float4*)(yrow + 36);
    }
    half8 a0, a1;
    a0[0]=(_Float16)v0.x; a0[1]=(_Float16)v0.y; a0[2]=(_Float16)v0.z; a0[3]=(_Float16)v0.w;
    a0[4]=(_Float16)v1.x; a0[5]=(_Float16)v1.y; a0[6]=(_Float16)v1.z; a0[7]=(_Float16)v1.w;
    a1[0]=(_Float16)v2.x; a1[1]=(_Float16)v2.y; a1[2]=(_Float16)v2.z; a1[3]=(_Float16)v2.w;
    a1[4]=(_Float16)v3.x; a1[5]=(_Float16)v3.y; a1[6]=(_Float16)v3.z; a1[7]=(_Float16)v3.w;

    f32x4 acc[8];
#pragma unroll
    for (int t = 0; t < 8; ++t) acc[t] = (f32x4){0.f, 0.f, 0.f, 0.f};
#pragma unroll
    for (int t = 0; t < 8; ++t) {
      half8 b0 = *(const half8*)(&W[(t * 16 + c) * GSTR + q * 8]);
      half8 b1 = *(const half8*)(&W[(t * 16 + c) * GSTR + 32 + q * 8]);
      acc[t] = __builtin_amdgcn_mfma_f32_16x16x32_f16(a0, b0, acc[t], 0, 0, 0);
      acc[t] = __builtin_amdgcn_mfma_f32_16x16x32_f16(a1, b1, acc[t], 0, 0, 0);
    }
#pragma unroll
    for (int t = 0; t < 4; ++t) {
#pragma unroll
      for (int i = 0; i < 4; ++i) {
        int n = n0 + q * 4 + i;
        if (n < N) {
          XL16[(size_t)n * HDIM + t * 16 + c] = (_Float16)acc[t][i];
          XR[(size_t)n * HDIM + t * 16 + c] = acc[t + 4][i];
        }
      }
    }
  }
}

// ======================= k5: GRU via f16 MFMA + heads =======================
__global__ void __launch_bounds__(256) k5_gru_mfma(const float* __restrict__ Y,
                       const _Float16* __restrict__ Wt,
                       const float* __restrict__ bi, const float* __restrict__ bh,
                       const float* __restrict__ huW, const float* __restrict__ hub,
                       const float* __restrict__ hfW, const float* __restrict__ hfb,
                       const float* __restrict__ hoW, const float* __restrict__ hob,
                       const float* __restrict__ hcW, const float* __restrict__ hcb,
                       float* __restrict__ out, int N) {
  __shared__ _Float16 W[192 * GSTR];
  __shared__ float BS[192];
  __shared__ float BHN[64];
  for (int i = threadIdx.x; i < 192 * GSTR / 8; i += 256)
    ((int4*)W)[i] = ((const int4*)Wt)[i];
  for (int i = threadIdx.x; i < 192; i += 256) BS[i] = bi[i] + (i < 128 ? bh[i] : 0.f);
  for (int i = threadIdx.x; i < 64; i += 256) BHN[i] = bh[128 + i];
  __syncthreads();

  int wave = blockIdx.x * 4 + (threadIdx.x >> 6);
  int nwaves = gridDim.x * 4;
  int lane = threadIdx.x & 63;
  int c = lane & 15, q = lane >> 4;

  float hu_[4], hf_[4], ho_[4], hc_[4];
#pragma unroll
  for (int t = 0; t < 4; ++t) {
    hu_[t] = huW[t * 16 + c];
    hf_[t] = hfW[t * 16 + c];
    ho_[t] = hoW[t * 16 + c];
    hc_[t] = hcW[t * 16 + c];
  }
  float hub0 = hub[0], hfb0 = hfb[0], hob0 = hob[0], hcb0 = hcb[0];

  for (int n0 = wave * 16; n0 < N; n0 += nwaves * 16) {
    bool okrow = (n0 + c) < N;
    const float* yrow = Y + (size_t)(n0 + c) * HDIM + q * 8;
    float4 v0 = {0,0,0,0}, v1 = {0,0,0,0}, v2 = {0,0,0,0}, v3 = {0,0,0,0};
    if (okrow) {
      v0 = *(const float4*)(yrow);
      v1 = *(const float4*)(yrow + 4);
      v2 = *(const float4*)(yrow + 32);
      v3 = *(const float4*)(yrow + 36);
    }
    half8 a0, a1;
    a0[0]=(_Float16)v0.x; a0[1]=(_Float16)v0.y; a0[2]=(_Float16)v0.z; a0[3]=(_Float16)v0.w;
    a0[4]=(_Float16)v1.x; a0[5]=(_Float16)v1.y; a0[6]=(_Float16)v1.z; a0[7]=(_Float16)v1.w;
    a1[0]=(_Float16)v2.x; a1[1]=(_Float16)v2.y; a1[2]=(_Float16)v2.z; a1[3]=(_Float16)v2.w;
    a1[4]=(_Float16)v3.x; a1[5]=(_Float16)v3.y; a1[6]=(_Float16)v3.z; a1[7]=(_Float16)v3.w;

    f32x4 acc[12];
#pragma unroll
    for (int t = 0; t < 12; ++t) acc[t] = (f32x4){0.f, 0.f, 0.f, 0.f};
#pragma unroll
    for (int t = 0; t < 12; ++t) {
      half8 b0 = *(const half8*)(&W[(t * 16 + c) * GSTR + q * 8]);
      half8 b1 = *(const half8*)(&W[(t * 16 + c) * GSTR + 32 + q * 8]);
      acc[t] = __builtin_amdgcn_mfma_f32_16x16x32_f16(a0, b0, acc[t], 0, 0, 0);
      acc[t] = __builtin_amdgcn_mfma_f32_16x16x32_f16(a1, b1, acc[t], 0, 0, 0);
    }

    float hv[4][4];
#pragma unroll
    for (int t = 0; t < 4; ++t) {
      int cr = t * 16 + c;
      float bsr = BS[cr], bsz = BS[64 + cr], bsn = BS[128 + cr], bhn = BHN[cr];
#pragma unroll
      for (int i = 0; i < 4; ++i) {
        float r = sigmoidf_(acc[t][i] + bsr);
        float z = sigmoidf_(acc[t + 4][i] + bsz);
        float nn = tanhf(acc[t + 8][i] + bsn + r * bhn);
        hv[t][i] = (1.f - z) * nn;
      }
    }
#pragma unroll
    for (int i = 0; i < 4; ++i) {
      float pu = 0.f, pf = 0.f, po = 0.f, pc = 0.f;
#pragma unroll
      for (int t = 0; t < 4; ++t) {
        pu += hv[t][i] * hu_[t];
        pf += hv[t][i] * hf_[t];
        po += hv[t][i] * ho_[t];
        pc += hv[t][i] * hc_[t];
      }
      pu = reduce16(pu); pf = reduce16(pf); po = reduce16(po); pc = reduce16(pc);
      int n = n0 + q * 4 + i;
      if (n < N) {
        if (c == 0) out[n]         = sigmoidf_(pu + hub0);
        if (c == 1) out[N + n]     = sigmoidf_(pf + hfb0);
        if (c == 2) out[2 * N + n] = fmaxf(po + hob0, 0.f);
        if (c == 3) out[3 * N + n] = sigmoidf_(pc + hcb0);
      }
    }
  }
}

// ======================= launch =======================
extern "C" void kernel_launch(void* const* d_in, const int* in_sizes, int n_in,
                              void* d_out, int out_size, void* d_ws, size_t ws_size,
                              hipStream_t stream) {
  const float* nf    = (const float*)d_in[0];
  const int*   ei    = (const int*)d_in[1];
  const float* projW = (const float*)d_in[2];
  const float* projB = (const float*)d_in[3];
  const float* g1Wl  = (const float*)d_in[4];
  const float* g1Wr  = (const float*)d_in[5];
  const float* g1att = (const float*)d_in[6];
  const float* g1b   = (const float*)d_in[7];
  const float* g2Wl  = (const float*)d_in[8];
  const float* g2Wr  = (const float*)d_in[9];
  const float* g2att = (const float*)d_in[10];
  const float* g2b   = (const float*)d_in[11];
  const float* ln1g  = (const float*)d_in[12];
  const float* ln1b  = (const float*)d_in[13];
  const float* ln2g  = (const float*)d_in[14];
  const float* ln2b  = (const float*)d_in[15];
  const float* gruWi = (const float*)d_in[16];
  // d_in[17] = gru_Wh, unused (h0 = 0)
  const float* gruBi = (const float*)d_in[18];
  const float* gruBh = (const float*)d_in[19];
  const float* huW = (const float*)d_in[20];
  const float* hub = (const float*)d_in[21];
  const float* hfW = (const float*)d_in[22];
  const float* hfb = (const float*)d_in[23];
  const float* hoW = (const float*)d_in[24];
  const float* hob = (const float*)d_in[25];
  const float* hcW = (const float*)d_in[26];
  const float* hcb = (const float*)d_in[27];
  float* out = (float*)d_out;

  const int N = in_sizes[0] / NDIM;
  const int E = in_sizes[1] / 2;
  int bsh = 8;
  while (((N - 1) >> bsh) >= NB) ++bsh;
  const int nbu = (N + (1 << bsh) - 1) >> bsh;

  char* ws = (char*)d_ws;
  size_t off = 0;
  auto carve = [&](size_t bytes) { void* p = ws + off; off += (bytes + 255) & ~size_t(255); return p; };
  _Float16*  XL16    = (_Float16*)carve(sizeof(_Float16) * N * HDIM);
  float*     XR      = (float*)carve(sizeof(float) * N * HDIM);
  float*     Y       = (float*)carve(sizeof(float) * N * HDIM);
  long long* pairs   = (long long*)carve(sizeof(long long) * E);
  int*       csr_src = (int*)carve(sizeof(int) * E);
  int*       deg     = (int*)carve(sizeof(int) * N);
  int*       row_off = (int*)carve(sizeof(int) * N);
  int*       hist    = (int*)carve(sizeof(int) * NB);
  int*       bbase   = (int*)carve(sizeof(int) * (NB + 1));
  int*       bcur    = (int*)carve(sizeof(int) * NB);
  float*     Wfl     = (float*)carve(sizeof(float) * NDIM * HDIM);
  float*     Wfr     = (float*)carve(sizeof(float) * NDIM * HDIM);
  float*     bfl     = (float*)carve(sizeof(float) * HDIM);
  float*     bfr     = (float*)carve(sizeof(float) * HDIM);
  _Float16*  Wt      = (_Float16*)carve(sizeof(_Float16) * 192 * GSTR);
  _Float16*  Wb      = (_Float16*)carve(sizeof(_Float16) * 128 * GSTR);

  const int BLK = 256;
  dim3 b(BLK);
  dim3 gridWaveN((N + 3) / 4);
  dim3 gridBin((E + BLK * EPB - 1) / (BLK * EPB));

  // ---- CSR build ----
  (void)hipMemsetAsync(hist, 0, sizeof(int) * NB, stream);
  k_hist<<<dim3(256), b, 0, stream>>>(ei + E, hist, E, bsh);
  k_prefix<<<dim3(1), dim3(NB), 0, stream>>>(hist, bbase, bcur);
  k_bin<<<gridBin, b, 0, stream>>>(ei, pairs, bcur, E, bsh);
  k_csr<<<dim3(nbu), b, 0, stream>>>(pairs, bbase, row_off, deg, csr_src, N, bsh);

  // ---- weight prep (merged) ----
  k_wprep<<<dim3(84), b, 0, stream>>>(projW, projB, g1Wl, g1Wr, gruWi, g2Wl, g2Wr,
                                      Wfl, Wfr, bfl, bfr, Wt, Wb);

  // ---- pipeline ----
  k1_xlxr<<<gridWaveN, b, 0, stream>>>(nf, Wfl, Wfr, bfl, bfr, XL16, XR, N);
  k_agg<<<gridWaveN, b, 0, stream>>>(csr_src, row_off, deg, XL16, XR, g1att, g1b, ln1g, ln1b, Y, N);
  k3_mfma<<<dim3(800), b, 0, stream>>>(Y, Wb, XL16, XR, N);
  k_agg<<<gridWaveN, b, 0, stream>>>(csr_src, row_off, deg, XL16, XR, g2att, g2b, ln2g, ln2b, Y, N);
  k5_gru_mfma<<<dim3(800), b, 0, stream>>>(Y, Wt, gruBi, gruBh,
                                           huW, hub, hfW, hfb, hoW, hob, hcW, hcb, out, N);
}

// Round 12
// 366.156 us; speedup vs baseline: 4.4739x; 1.1215x over previous
//
#include <hip/hip_runtime.h>

#define NDIM 14
#define HDIM 64
#define NB 512         // scatter bucket slots (nbu <= NB used)
#define EPB 16         // edges per thread in k_bin
#define GSTR 72        // padded col stride (halfs) for LDS-staged f16 weights

typedef __attribute__((ext_vector_type(8))) _Float16 half8;
typedef __attribute__((ext_vector_type(2))) __fp16 fp16x2;   // builtin interop type
typedef __attribute__((ext_vector_type(4))) float f32x4;

static __device__ __forceinline__ float sigmoidf_(float x) { return 1.f / (1.f + __expf(-x)); }
static __device__ __forceinline__ float lrelu_(float x) { return x > 0.f ? x : 0.2f * x; }

static __device__ __forceinline__ float readlane_f(float x, int lane) {
  return __int_as_float(__builtin_amdgcn_readlane(__float_as_int(x), lane));
}

template <int CTRL>
static __device__ __forceinline__ float dpp_add_f(float x) {
  int v = __builtin_amdgcn_update_dpp(0, __float_as_int(x), CTRL, 0xF, 0xF, true);
  return x + __int_as_float(v);
}

// f32 sum over each 16-lane DPP row
static __device__ __forceinline__ float reduce16(float p) {
  p = dpp_add_f<0xB1>(p);
  p = dpp_add_f<0x4E>(p);
  p = dpp_add_f<0x141>(p);
  p = dpp_add_f<0x140>(p);
  return p;
}
// f32 sum within each 32-lane half
static __device__ __forceinline__ float head_reduce32(float p) {
  p = reduce16(p);
  p += __int_as_float(__builtin_amdgcn_ds_swizzle(__float_as_int(p), 0x401F));
  return p;
}
static __device__ __forceinline__ float full_reduce64(float p) {
  p = head_reduce32(p);
  p += __shfl_xor(p, 32, 64);
  return p;
}

// ---- packed f16 helpers ----
static __device__ __forceinline__ unsigned pk_add(unsigned a, unsigned b) {
  unsigned d; asm("v_pk_add_f16 %0, %1, %2" : "=v"(d) : "v"(a), "v"(b)); return d;
}
static __device__ __forceinline__ unsigned pk_mul(unsigned a, unsigned b) {
  unsigned d; asm("v_pk_mul_f16 %0, %1, %2" : "=v"(d) : "v"(a), "v"(b)); return d;
}
static __device__ __forceinline__ unsigned pk_max(unsigned a, unsigned b) {
  unsigned d; asm("v_pk_max_f16 %0, %1, %2" : "=v"(d) : "v"(a), "v"(b)); return d;
}
static __device__ __forceinline__ unsigned cvt_pk_u(float a, float b) {
  fp16x2 h = __builtin_amdgcn_cvt_pkrtz(a, b);
  unsigned u; __builtin_memcpy(&u, &h, 4); return u;
}
static __device__ __forceinline__ fp16x2 as_h2(unsigned u) {
  fp16x2 h; __builtin_memcpy(&h, &u, 4); return h;
}
static __device__ __forceinline__ float cvt_lo(unsigned u) {
  float r; asm("v_cvt_f32_f16 %0, %1" : "=v"(r) : "v"(u)); return r;
}
template <int CTRL>
static __device__ __forceinline__ unsigned pk_dpp_add(unsigned x) {
  unsigned v = (unsigned)__builtin_amdgcn_update_dpp(0, (int)x, CTRL, 0xF, 0xF, true);
  return pk_add(x, v);
}
// packed f16 sum within each 32-lane half: 4 DPP + 1 swizzle
static __device__ __forceinline__ unsigned pk_reduce32(unsigned p) {
  p = pk_dpp_add<0xB1>(p);     // xor1
  p = pk_dpp_add<0x4E>(p);     // xor2
  p = pk_dpp_add<0x141>(p);    // 8-group mirror
  p = pk_dpp_add<0x140>(p);    // 16-group mirror
  p = pk_add(p, (unsigned)__builtin_amdgcn_ds_swizzle((int)p, 0x401F)); // xor16
  return p;
}

// ======================= CSR build (direct-binned, padded buckets) =======================
__global__ void k_binit(int* __restrict__ bcur, int cap) {
  int i = blockIdx.x * blockDim.x + threadIdx.x;
  if (i < NB) bcur[i] = i * cap;
}

// bin edges into per-bucket padded slices; block-local LDS counts + bulk claims
__global__ void __launch_bounds__(256) k_bin(const int* __restrict__ ei,
                      long long* __restrict__ pairs, int* __restrict__ bucket_cur,
                      int E, int bsh) {
  __shared__ int h[NB];
  __shared__ int gb[NB];
  int t = threadIdx.x;
  for (int i = t; i < NB; i += 256) h[i] = 0;
  __syncthreads();
  int c0 = blockIdx.x * (256 * EPB);
  long long pr[EPB];
  int br[EPB];
#pragma unroll
  for (int i = 0; i < EPB; ++i) {
    int e = c0 + t + i * 256;
    if (e < E) {
      int s = ei[e], d = ei[E + e];
      int b = d >> bsh;
      int r = atomicAdd(&h[b], 1);
      pr[i] = ((long long)d << 32) | (unsigned)s;
      br[i] = b | (r << 9);
    } else br[i] = -1;
  }
  __syncthreads();
  for (int i = t; i < NB; i += 256)
    if (h[i]) gb[i] = atomicAdd(&bucket_cur[i], h[i]);
  __syncthreads();
#pragma unroll
  for (int i = 0; i < EPB; ++i) {
    if (br[i] >= 0) pairs[gb[br[i] & (NB - 1)] + (br[i] >> 9)] = pr[i];
  }
}

// per-bucket CSR: degree hist + scan + placement in LDS. One block per bucket.
__global__ void __launch_bounds__(256) k_csr(const long long* __restrict__ pairs,
                      const int* __restrict__ bcur_final, int* __restrict__ row_off,
                      int* __restrict__ deg, int* __restrict__ csr_src,
                      int N, int bsh, int cap) {
  __shared__ int h[1024];
  __shared__ int cu[1024];
  __shared__ int wtot[4];
  int b = blockIdx.x;
  int node0 = b << bsh;
  int range = 1 << bsh;
  int nr = N - node0; if (nr > range) nr = range;
  if (nr <= 0) return;
  int e0 = b * cap, e1 = bcur_final[b];
  int tid = threadIdx.x;
  for (int i = tid; i < range; i += 256) h[i] = 0;
  __syncthreads();
  for (int e = e0 + tid; e < e1; e += 256)
    atomicAdd(&h[(int)(pairs[e] >> 32) - node0], 1);
  __syncthreads();
  if (range == 256) {
    int lane = tid & 63, wid = tid >> 6;
    int v = (tid < nr) ? h[tid] : 0;
    int x = v;
#pragma unroll
    for (int m = 1; m <= 32; m <<= 1) {
      int t2 = __shfl_up(x, m, 64);
      if (lane >= m) x += t2;
    }
    if (lane == 63) wtot[wid] = x;
    __syncthreads();
    int woff = 0;
#pragma unroll
    for (int w = 0; w < 4; ++w) woff += (w < wid) ? wtot[w] : 0;
    int excl = woff + x - v;
    if (tid < nr) {
      row_off[node0 + tid] = e0 + excl;
      deg[node0 + tid] = v;
      cu[tid] = excl;
    }
  } else {
    if (tid == 0) {
      int acc = 0;
      for (int i = 0; i < nr; ++i) {
        row_off[node0 + i] = e0 + acc;
        deg[node0 + i] = h[i];
        cu[i] = acc;
        acc += h[i];
      }
    }
  }
  __syncthreads();
  for (int e = e0 + tid; e < e1; e += 256) {
    long long pk = pairs[e];
    int d = (int)(pk >> 32), s = (int)pk;
    int p = atomicAdd(&cu[d - node0], 1);
    csr_src[e0 + p] = s;
  }
}

// ======================= merged weight prep =======================
__global__ void k_wprep(const float* __restrict__ projW, const float* __restrict__ projB,
                        const float* __restrict__ Wl1, const float* __restrict__ Wr1,
                        const float* __restrict__ Wi, const float* __restrict__ Wl2,
                        const float* __restrict__ Wr2,
                        float* __restrict__ Wfl, float* __restrict__ Wfr,
                        float* __restrict__ bfl, float* __restrict__ bfr,
                        _Float16* __restrict__ Wt, _Float16* __restrict__ Wb) {
  int blk = blockIdx.x;
  if (blk < 4) {
    int t = blk * 256 + threadIdx.x;
    int total = (NDIM + 1) * HDIM;
    if (t >= total) return;
    int r = t / HDIM, c = t % HDIM;
    float al = 0.f, ar = 0.f;
    if (r < NDIM) {
      for (int k = 0; k < HDIM; ++k) {
        float w = projW[r * HDIM + k];
        al += w * Wl1[k * HDIM + c];
        ar += w * Wr1[k * HDIM + c];
      }
      Wfl[r * HDIM + c] = al;
      Wfr[r * HDIM + c] = ar;
    } else {
      for (int k = 0; k < HDIM; ++k) {
        float w = projB[k];
        al += w * Wl1[k * HDIM + c];
        ar += w * Wr1[k * HDIM + c];
      }
      bfl[c] = al;
      bfr[c] = ar;
    }
  } else if (blk < 52) {
    int t = (blk - 4) * 256 + threadIdx.x;
    if (t >= 192 * 64) return;
    int col = t / 64, row = t % 64;
    Wt[col * GSTR + row] = (_Float16)Wi[row * 192 + col];
  } else {
    int t = (blk - 52) * 256 + threadIdx.x;
    if (t >= 128 * 64) return;
    int col = t >> 6, row = t & 63;
    float v = (col < 64) ? Wl2[row * 64 + col] : Wr2[row * 64 + (col - 64)];
    Wb[col * GSTR + row] = (_Float16)v;
  }
}

// ======================= k1: XL1(f16)/XR1(f32) from node features =======================
__global__ void k1_xlxr(const float* __restrict__ nf, const float* __restrict__ Wfl,
                        const float* __restrict__ Wfr, const float* __restrict__ bfl,
                        const float* __restrict__ bfr, _Float16* __restrict__ XL16,
                        float* __restrict__ XR, int N) {
  int n = blockIdx.x * (blockDim.x >> 6) + (threadIdx.x >> 6);
  int j = threadIdx.x & 63;
  if (n >= N) return;
  float nfv = (j < NDIM) ? nf[n * NDIM + j] : 0.f;
  float al = bfl[j], ar = bfr[j];
#pragma unroll
  for (int k = 0; k < NDIM; ++k) {
    float xk = readlane_f(nfv, k);
    al += xk * Wfl[k * HDIM + j];
    ar += xk * Wfr[k * HDIM + j];
  }
  XL16[n * HDIM + j] = (_Float16)al;
  XR[n * HDIM + j] = ar;
}

// ======================= k_agg: packed-f16 pull-aggregate + softmax + ELU + LN =======================
__global__ void k_agg(const int* __restrict__ csr_src, const int* __restrict__ row_off,
                      const int* __restrict__ deg, const _Float16* __restrict__ XL16,
                      const float* __restrict__ XR, const float* __restrict__ att,
                      const float* __restrict__ gb, const float* __restrict__ lng,
                      const float* __restrict__ lnb, float* __restrict__ Y, int N) {
  int n = blockIdx.x * (blockDim.x >> 6) + (threadIdx.x >> 6);
  int j = threadIdx.x & 63;
  if (n >= N) return;
  float xr = XR[n * HDIM + j];
  float attv = att[j];
  unsigned xr_pk  = cvt_pk_u(xr, xr);
  unsigned att_pk = cvt_pk_u(attv, attv);
  unsigned c02_pk = 0x32663266u;                    // (0.2, 0.2) f16
  fp16x2 one_pk = as_h2(0x3C003C00u);               // (1.0, 1.0) f16
  const unsigned short* XLu = (const unsigned short*)XL16;
  unsigned ju = (unsigned)j;

  // self-loop (f32 path)
  float xl = (float)XL16[(size_t)n * HDIM + j];
  float p = head_reduce32(lrelu_(xl + xr) * attv);
  float ex = __expf(p);
  float acc0 = ex * xl, acc1 = 0.f;
  float den0 = ex, den1 = 0.f;

  int base = row_off[n], cnt = deg[n];
  for (int c0 = 0; c0 < cnt; c0 += 64) {
    int m_ = cnt - c0; if (m_ > 64) m_ = 64;
    int sidx = (j < m_) ? csr_src[base + c0 + j] : 0;
    int npairs = m_ >> 1;
    int pp = 0;
    // ---- full 8-pair groups, unmasked ----
    for (; pp + 8 <= npairs; pp += 8) {
      unsigned x[8];
#pragma unroll
      for (int u = 0; u < 8; ++u) {
        int sa = __builtin_amdgcn_readlane(sidx, 2 * (pp + u));
        int sb = __builtin_amdgcn_readlane(sidx, 2 * (pp + u) + 1);
        unsigned short ua = XLu[((unsigned)sa << 6) + ju];
        unsigned short ub = XLu[((unsigned)sb << 6) + ju];
        x[u] = (unsigned)ua | ((unsigned)ub << 16);
      }
#pragma unroll
      for (int u = 0; u < 8; ++u) {
        unsigned t = pk_add(x[u], xr_pk);
        unsigned lr = pk_max(t, pk_mul(t, c02_pk));
        unsigned sc = pk_mul(lr, att_pk);
        sc = pk_reduce32(sc);
        float s_a = cvt_lo(sc), s_b = cvt_lo(sc >> 16);
        float e_a = __expf(s_a), e_b = __expf(s_b);
        fp16x2 exk = __builtin_amdgcn_cvt_pkrtz(e_a, e_b);
        if (u & 1) {
          acc1 = __builtin_amdgcn_fdot2(as_h2(x[u]), exk, acc1, false);
          den1 = __builtin_amdgcn_fdot2(exk, one_pk, den1, false);
        } else {
          acc0 = __builtin_amdgcn_fdot2(as_h2(x[u]), exk, acc0, false);
          den0 = __builtin_amdgcn_fdot2(exk, one_pk, den0, false);
        }
      }
    }
    // ---- remaining pairs ----
    for (; pp < npairs; ++pp) {
      int sa = __builtin_amdgcn_readlane(sidx, 2 * pp);
      int sb = __builtin_amdgcn_readlane(sidx, 2 * pp + 1);
      unsigned short ua = XLu[((unsigned)sa << 6) + ju];
      unsigned short ub = XLu[((unsigned)sb << 6) + ju];
      unsigned xu = (unsigned)ua | ((unsigned)ub << 16);
      unsigned t = pk_add(xu, xr_pk);
      unsigned lr = pk_max(t, pk_mul(t, c02_pk));
      unsigned sc = pk_mul(lr, att_pk);
      sc = pk_reduce32(sc);
      float s_a = cvt_lo(sc), s_b = cvt_lo(sc >> 16);
      float e_a = __expf(s_a), e_b = __expf(s_b);
      fp16x2 exk = __builtin_amdgcn_cvt_pkrtz(e_a, e_b);
      acc0 = __builtin_amdgcn_fdot2(as_h2(xu), exk, acc0, false);
      den0 = __builtin_amdgcn_fdot2(exk, one_pk, den0, false);
    }
    if (m_ & 1) {   // odd edge, f32 path
      int s = __builtin_amdgcn_readlane(sidx, m_ - 1);
      float xls = (float)XL16[(size_t)s * HDIM + j];
      float pq = head_reduce32(lrelu_(xls + xr) * attv);
      float ee = __expf(pq);
      acc0 += ee * xls;
      den0 += ee;
    }
  }

  float acc = acc0 + acc1;
  float den = den0 + den1;
  float y = acc / (den + 1e-16f) + gb[j];
  y = y > 0.f ? y : __expf(y) - 1.f;
  float mu = full_reduce64(y) * (1.f / 64.f);
  float d = y - mu;
  float var = full_reduce64(d * d) * (1.f / 64.f);
  Y[n * HDIM + j] = d * rsqrtf(var + 1e-5f) * lng[j] + lnb[j];
}

// ======================= k3: Y -> XL2(f16)/XR2(f32) via f16 MFMA =======================
__global__ void __launch_bounds__(256) k3_mfma(const float* __restrict__ Y,
                      const _Float16* __restrict__ Wb, _Float16* __restrict__ XL16,
                      float* __restrict__ XR, int N) {
  __shared__ _Float16 W[128 * GSTR];
  for (int i = threadIdx.x; i < 128 * GSTR / 8; i += 256)
    ((int4*)W)[i] = ((const int4*)Wb)[i];
  __syncthreads();
  int wave = blockIdx.x * 4 + (threadIdx.x >> 6);
  int nwaves = gridDim.x * 4;
  int lane = threadIdx.x & 63;
  int c = lane & 15, q = lane >> 4;
  for (int n0 = wave * 16; n0 < N; n0 += nwaves * 16) {
    bool okrow = (n0 + c) < N;
    const float* yrow = Y + (size_t)(n0 + c) * HDIM + q * 8;
    float4 v0 = {0,0,0,0}, v1 = {0,0,0,0}, v2 = {0,0,0,0}, v3 = {0,0,0,0};
    if (okrow) {
      v0 = *(const float4*)(yrow);
      v1 = *(const float4*)(yrow + 4);
      v2 = *(const float4*)(yrow + 32);
      v3 = *(const float4*)(yrow + 36);
    }
    half8 a0, a1;
    a0[0]=(_Float16)v0.x; a0[1]=(_Float16)v0.y; a0[2]=(_Float16)v0.z; a0[3]=(_Float16)v0.w;
    a0[4]=(_Float16)v1.x; a0[5]=(_Float16)v1.y; a0[6]=(_Float16)v1.z; a0[7]=(_Float16)v1.w;
    a1[0]=(_Float16)v2.x; a1[1]=(_Float16)v2.y; a1[2]=(_Float16)v2.z; a1[3]=(_Float16)v2.w;
    a1[4]=(_Float16)v3.x; a1[5]=(_Float16)v3.y; a1[6]=(_Float16)v3.z; a1[7]=(_Float16)v3.w;

    f32x4 acc[8];
#pragma unroll
    for (int t = 0; t < 8; ++t) acc[t] = (f32x4){0.f, 0.f, 0.f, 0.f};
#pragma unroll
    for (int t = 0; t < 8; ++t) {
      half8 b0 = *(const half8*)(&W[(t * 16 + c) * GSTR + q * 8]);
      half8 b1 = *(const half8*)(&W[(t * 16 + c) * GSTR + 32 + q * 8]);
      acc[t] = __builtin_amdgcn_mfma_f32_16x16x32_f16(a0, b0, acc[t], 0, 0, 0);
      acc[t] = __builtin_amdgcn_mfma_f32_16x16x32_f16(a1, b1, acc[t], 0, 0, 0);
    }
#pragma unroll
    for (int t = 0; t < 4; ++t) {
#pragma unroll
      for (int i = 0; i < 4; ++i) {
        int n = n0 + q * 4 + i;
        if (n < N) {
          XL16[(size_t)n * HDIM + t * 16 + c] = (_Float16)acc[t][i];
          XR[(size_t)n * HDIM + t * 16 + c] = acc[t + 4][i];
        }
      }
    }
  }
}

// ======================= k5: GRU via f16 MFMA + heads =======================
__global__ void __launch_bounds__(256) k5_gru_mfma(const float* __restrict__ Y,
                       const _Float16* __restrict__ Wt,
                       const float* __restrict__ bi, const float* __restrict__ bh,
                       const float* __restrict__ huW, const float* __restrict__ hub,
                       const float* __restrict__ hfW, const float* __restrict__ hfb,
                       const float* __restrict__ hoW, const float* __restrict__ hob,
                       const float* __restrict__ hcW, const float* __restrict__ hcb,
                       float* __restrict__ out, int N) {
  __shared__ _Float16 W[192 * GSTR];
  __shared__ float BS[192];
  __shared__ float BHN[64];
  for (int i = threadIdx.x; i < 192 * GSTR / 8; i += 256)
    ((int4*)W)[i] = ((const int4*)Wt)[i];
  for (int i = threadIdx.x; i < 192; i += 256) BS[i] = bi[i] + (i < 128 ? bh[i] : 0.f);
  for (int i = threadIdx.x; i < 64; i += 256) BHN[i] = bh[128 + i];
  __syncthreads();

  int wave = blockIdx.x * 4 + (threadIdx.x >> 6);
  int nwaves = gridDim.x * 4;
  int lane = threadIdx.x & 63;
  int c = lane & 15, q = lane >> 4;

  float hu_[4], hf_[4], ho_[4], hc_[4];
#pragma unroll
  for (int t = 0; t < 4; ++t) {
    hu_[t] = huW[t * 16 + c];
    hf_[t] = hfW[t * 16 + c];
    ho_[t] = hoW[t * 16 + c];
    hc_[t] = hcW[t * 16 + c];
  }
  float hub0 = hub[0], hfb0 = hfb[0], hob0 = hob[0], hcb0 = hcb[0];

  for (int n0 = wave * 16; n0 < N; n0 += nwaves * 16) {
    bool okrow = (n0 + c) < N;
    const float* yrow = Y + (size_t)(n0 + c) * HDIM + q * 8;
    float4 v0 = {0,0,0,0}, v1 = {0,0,0,0}, v2 = {0,0,0,0}, v3 = {0,0,0,0};
    if (okrow) {
      v0 = *(const float4*)(yrow);
      v1 = *(const float4*)(yrow + 4);
      v2 = *(const float4*)(yrow + 32);
      v3 = *(const float4*)(yrow + 36);
    }
    half8 a0, a1;
    a0[0]=(_Float16)v0.x; a0[1]=(_Float16)v0.y; a0[2]=(_Float16)v0.z; a0[3]=(_Float16)v0.w;
    a0[4]=(_Float16)v1.x; a0[5]=(_Float16)v1.y; a0[6]=(_Float16)v1.z; a0[7]=(_Float16)v1.w;
    a1[0]=(_Float16)v2.x; a1[1]=(_Float16)v2.y; a1[2]=(_Float16)v2.z; a1[3]=(_Float16)v2.w;
    a1[4]=(_Float16)v3.x; a1[5]=(_Float16)v3.y; a1[6]=(_Float16)v3.z; a1[7]=(_Float16)v3.w;

    f32x4 acc[12];
#pragma unroll
    for (int t = 0; t < 12; ++t) acc[t] = (f32x4){0.f, 0.f, 0.f, 0.f};
#pragma unroll
    for (int t = 0; t < 12; ++t) {
      half8 b0 = *(const half8*)(&W[(t * 16 + c) * GSTR + q * 8]);
      half8 b1 = *(const half8*)(&W[(t * 16 + c) * GSTR + 32 + q * 8]);
      acc[t] = __builtin_amdgcn_mfma_f32_16x16x32_f16(a0, b0, acc[t], 0, 0, 0);
      acc[t] = __builtin_amdgcn_mfma_f32_16x16x32_f16(a1, b1, acc[t], 0, 0, 0);
    }

    float hv[4][4];
#pragma unroll
    for (int t = 0; t < 4; ++t) {
      int cr = t * 16 + c;
      float bsr = BS[cr], bsz = BS[64 + cr], bsn = BS[128 + cr], bhn = BHN[cr];
#pragma unroll
      for (int i = 0; i < 4; ++i) {
        float r = sigmoidf_(acc[t][i] + bsr);
        float z = sigmoidf_(acc[t + 4][i] + bsz);
        float nn = tanhf(acc[t + 8][i] + bsn + r * bhn);
        hv[t][i] = (1.f - z) * nn;
      }
    }
#pragma unroll
    for (int i = 0; i < 4; ++i) {
      float pu = 0.f, pf = 0.f, po = 0.f, pc = 0.f;
#pragma unroll
      for (int t = 0; t < 4; ++t) {
        pu += hv[t][i] * hu_[t];
        pf += hv[t][i] * hf_[t];
        po += hv[t][i] * ho_[t];
        pc += hv[t][i] * hc_[t];
      }
      pu = reduce16(pu); pf = reduce16(pf); po = reduce16(po); pc = reduce16(pc);
      int n = n0 + q * 4 + i;
      if (n < N) {
        if (c == 0) out[n]         = sigmoidf_(pu + hub0);
        if (c == 1) out[N + n]     = sigmoidf_(pf + hfb0);
        if (c == 2) out[2 * N + n] = fmaxf(po + hob0, 0.f);
        if (c == 3) out[3 * N + n] = sigmoidf_(pc + hcb0);
      }
    }
  }
}

// ======================= launch =======================
extern "C" void kernel_launch(void* const* d_in, const int* in_sizes, int n_in,
                              void* d_out, int out_size, void* d_ws, size_t ws_size,
                              hipStream_t stream) {
  const float* nf    = (const float*)d_in[0];
  const int*   ei    = (const int*)d_in[1];
  const float* projW = (const float*)d_in[2];
  const float* projB = (const float*)d_in[3];
  const float* g1Wl  = (const float*)d_in[4];
  const float* g1Wr  = (const float*)d_in[5];
  const float* g1att = (const float*)d_in[6];
  const float* g1b   = (const float*)d_in[7];
  const float* g2Wl  = (const float*)d_in[8];
  const float* g2Wr  = (const float*)d_in[9];
  const float* g2att = (const float*)d_in[10];
  const float* g2b   = (const float*)d_in[11];
  const float* ln1g  = (const float*)d_in[12];
  const float* ln1b  = (const float*)d_in[13];
  const float* ln2g  = (const float*)d_in[14];
  const float* ln2b  = (const float*)d_in[15];
  const float* gruWi = (const float*)d_in[16];
  // d_in[17] = gru_Wh, unused (h0 = 0)
  const float* gruBi = (const float*)d_in[18];
  const float* gruBh = (const float*)d_in[19];
  const float* huW = (const float*)d_in[20];
  const float* hub = (const float*)d_in[21];
  const float* hfW = (const float*)d_in[22];
  const float* hfb = (const float*)d_in[23];
  const float* hoW = (const float*)d_in[24];
  const float* hob = (const float*)d_in[25];
  const float* hcW = (const float*)d_in[26];
  const float* hcb = (const float*)d_in[27];
  float* out = (float*)d_out;

  const int N = in_sizes[0] / NDIM;
  const int E = in_sizes[1] / 2;
  int bsh = 8;
  while (((N - 1) >> bsh) >= NB) ++bsh;
  const int nbu = (N + (1 << bsh) - 1) >> bsh;
  const int cap = (E + nbu - 1) / nbu + 768;   // +12 sigma over Poisson mean

  char* ws = (char*)d_ws;
  size_t off = 0;
  auto carve = [&](size_t bytes) { void* p = ws + off; off += (bytes + 255) & ~size_t(255); return p; };
  _Float16*  XL16    = (_Float16*)carve(sizeof(_Float16) * N * HDIM);
  float*     XR      = (float*)carve(sizeof(float) * N * HDIM);
  float*     Y       = (float*)carve(sizeof(float) * N * HDIM);
  long long* pairs   = (long long*)carve(sizeof(long long) * (size_t)nbu * cap);
  int*       csr_src = (int*)carve(sizeof(int) * (size_t)nbu * cap);
  int*       deg     = (int*)carve(sizeof(int) * N);
  int*       row_off = (int*)carve(sizeof(int) * N);
  int*       bcur    = (int*)carve(sizeof(int) * NB);
  float*     Wfl     = (float*)carve(sizeof(float) * NDIM * HDIM);
  float*     Wfr     = (float*)carve(sizeof(float) * NDIM * HDIM);
  float*     bfl     = (float*)carve(sizeof(float) * HDIM);
  float*     bfr     = (float*)carve(sizeof(float) * HDIM);
  _Float16*  Wt      = (_Float16*)carve(sizeof(_Float16) * 192 * GSTR);
  _Float16*  Wb      = (_Float16*)carve(sizeof(_Float16) * 128 * GSTR);

  const int BLK = 256;
  dim3 b(BLK);
  dim3 gridWaveN((N + 3) / 4);
  dim3 gridBin((E + BLK * EPB - 1) / (BLK * EPB));

  // ---- CSR build (direct-binned) ----
  k_binit<<<dim3(2), b, 0, stream>>>(bcur, cap);
  k_bin<<<gridBin, b, 0, stream>>>(ei, pairs, bcur, E, bsh);
  k_csr<<<dim3(nbu), b, 0, stream>>>(pairs, bcur, row_off, deg, csr_src, N, bsh, cap);

  // ---- weight prep (merged) ----
  k_wprep<<<dim3(84), b, 0, stream>>>(projW, projB, g1Wl, g1Wr, gruWi, g2Wl, g2Wr,
                                      Wfl, Wfr, bfl, bfr, Wt, Wb);

  // ---- pipeline ----
  k1_xlxr<<<gridWaveN, b, 0, stream>>>(nf, Wfl, Wfr, bfl, bfr, XL16, XR, N);
  k_agg<<<gridWaveN, b, 0, stream>>>(csr_src, row_off, deg, XL16, XR, g1att, g1b, ln1g, ln1b, Y, N);
  k3_mfma<<<dim3(800), b, 0, stream>>>(Y, Wb, XL16, XR, N);
  k_agg<<<gridWaveN, b, 0, stream>>>(csr_src, row_off, deg, XL16, XR, g2att, g2b, ln2g, ln2b, Y, N);
  k5_gru_mfma<<<dim3(800), b, 0, stream>>>(Y, Wt, gruBi, gruBh,
                                           huW, hub, hfW, hfb, hoW, hob, hcW, hcb, out, N);
}